// Round 2
// baseline (1383.398 us; speedup 1.0000x reference)
//
#include <hip/hip_runtime.h>
#include <hip/hip_bf16.h>
#include <math.h>

#define NB 16      // batch
#define CS 80      // spec channels
#define T1 1000    // mel frames
#define CT 512     // text channels
#define T2 200     // phonemes
#define CA 80      // attn channels
#define GD 256     // speaker dim
#define C2T 1024   // 2*Ct
#define C2S 160    // 2*Cs
#define TEMP_F 0.0005f

// ---------------------------------------------------------------------------
// speaker projections: kspk[b][c] = b_kspk[c] + g[b]·w_kspk[c], qspk likewise
// ---------------------------------------------------------------------------
__global__ void spk_kernel(const float* __restrict__ g,
                           const float* __restrict__ w_kspk, const float* __restrict__ b_kspk,
                           const float* __restrict__ w_qspk, const float* __restrict__ b_qspk,
                           float* __restrict__ kspk, float* __restrict__ qspk) {
    int i = blockIdx.x * 256 + threadIdx.x;
    const int NK = NB * CT;               // 8192
    if (i < NK) {
        int b = i >> 9, c = i & 511;
        float s = b_kspk[c];
        for (int j = 0; j < GD; j++) s += g[b * GD + j] * w_kspk[c * GD + j];
        kspk[i] = s;
    } else {
        int i2 = i - NK;
        if (i2 < NB * CS) {
            int b = i2 / CS, c = i2 - b * CS;
            float s = b_qspk[c];
            for (int j = 0; j < GD; j++) s += g[b * GD + j] * w_qspk[c * GD + j];
            qspk[i2] = s;
        }
    }
}

// ---------------------------------------------------------------------------
// x[b][c][t] = in[b][c][t] + spk[b][c]
// ---------------------------------------------------------------------------
template <int C, int T>
__global__ void addspk_kernel(const float* __restrict__ in, const float* __restrict__ spk,
                              float* __restrict__ outx) {
    int i = blockIdx.x * 256 + threadIdx.x;
    if (i < NB * C * T) {
        int ct = i / T;                 // == b*C + c
        outx[i] = in[i] + spk[ct];
    }
}

// ---------------------------------------------------------------------------
// k=3 SAME conv + ReLU.  out[b][co][t] = relu(bias[co] + sum_{ci,k} w[co][ci][k]*x[b][ci][t+k-1])
// grid: (ceil(T/256), COUT/16, B), block 256 = 64 t-lanes x 4 co-groups
// each thread computes 4 co (ty*4+j) x 4 t positions (tx + 64*i)
// ---------------------------------------------------------------------------
template <int CIN, int TTOT>
__global__ __launch_bounds__(256) void conv3_relu_kernel(const float* __restrict__ x,
                                                         const float* __restrict__ w,
                                                         const float* __restrict__ bias,
                                                         float* __restrict__ out) {
    constexpr int CIC = 8;
    __shared__ float XS[CIC][260];       // XS[cic][tt] = x[t0 + tt - 1], tt in [0,258)
    __shared__ float WS[16][CIC * 3];
    const int t0 = blockIdx.x * 256;
    const int co0 = blockIdx.y * 16;
    const int b = blockIdx.z;
    const int COUT = gridDim.y * 16;
    const int tid = threadIdx.x, tx = tid & 63, ty = tid >> 6;
    float acc[4][4] = {{0.f, 0.f, 0.f, 0.f}};
    const float* xb = x + (size_t)b * CIN * TTOT;

    for (int ci0 = 0; ci0 < CIN; ci0 += CIC) {
        __syncthreads();   // protect LDS from previous iteration's readers
        for (int idx = tid; idx < CIC * 258; idx += 256) {
            int cic = idx / 258, tt = idx - cic * 258;
            int gt = t0 + tt - 1;
            XS[cic][tt] = (gt >= 0 && gt < TTOT) ? xb[(ci0 + cic) * TTOT + gt] : 0.f;
        }
        for (int idx = tid; idx < 16 * CIC * 3; idx += 256) {
            int coc = idx / (CIC * 3), r = idx - coc * (CIC * 3);
            WS[coc][r] = w[(size_t)(co0 + coc) * (CIN * 3) + ci0 * 3 + r];
        }
        __syncthreads();
#pragma unroll
        for (int cic = 0; cic < CIC; cic++) {
#pragma unroll
            for (int i = 0; i < 4; i++) {
                int tl = tx + 64 * i;
                if (t0 + tl < TTOT) {
                    float x0 = XS[cic][tl], x1 = XS[cic][tl + 1], x2 = XS[cic][tl + 2];
#pragma unroll
                    for (int j = 0; j < 4; j++) {
                        int coc = ty * 4 + j;
                        acc[j][i] += WS[coc][cic * 3] * x0 + WS[coc][cic * 3 + 1] * x1 +
                                     WS[coc][cic * 3 + 2] * x2;
                    }
                }
            }
        }
    }
#pragma unroll
    for (int j = 0; j < 4; j++) {
        int co = co0 + ty * 4 + j;
        float bv = bias[co];
#pragma unroll
        for (int i = 0; i < 4; i++) {
            int t = t0 + tx + 64 * i;
            if (t < TTOT) out[((size_t)b * COUT + co) * TTOT + t] = fmaxf(acc[j][i] + bv, 0.f);
        }
    }
}

// ---------------------------------------------------------------------------
// 1x1 conv (optionally ReLU). grid (COUT, B), block 256 threads over t.
// ---------------------------------------------------------------------------
template <int CIN, int TTOT, bool RELU, int NT>
__global__ __launch_bounds__(256) void conv1x1_kernel(const float* __restrict__ x,
                                                      const float* __restrict__ w,
                                                      const float* __restrict__ bias,
                                                      float* __restrict__ out) {
    __shared__ float WS[CIN];
    const int co = blockIdx.x, b = blockIdx.y, tid = threadIdx.x;
    const int COUT = gridDim.x;
    for (int idx = tid; idx < CIN; idx += 256) WS[idx] = w[(size_t)co * CIN + idx];
    __syncthreads();
    float acc[NT];
#pragma unroll
    for (int i = 0; i < NT; i++) acc[i] = 0.f;
    const float* xb = x + (size_t)b * CIN * TTOT;
    for (int ci = 0; ci < CIN; ci++) {
        float wv = WS[ci];
#pragma unroll
        for (int i = 0; i < NT; i++) {
            int t = tid + 256 * i;
            if (t < TTOT) acc[i] += wv * xb[ci * TTOT + t];
        }
    }
    float bv = bias[co];
    float* ob = out + ((size_t)b * COUT + co) * TTOT;
#pragma unroll
    for (int i = 0; i < NT; i++) {
        int t = tid + 256 * i;
        if (t < TTOT) {
            float v = acc[i] + bv;
            ob[t] = RELU ? fmaxf(v, 0.f) : v;
        }
    }
}

// ---------------------------------------------------------------------------
// out[b][t] = sum_c x[b][c][t]^2
// ---------------------------------------------------------------------------
__global__ void sqsum_kernel(const float* __restrict__ x, float* __restrict__ out, int T) {
    int i = blockIdx.x * 256 + threadIdx.x;
    if (i < NB * T) {
        int b = i / T, t = i - b * T;
        float s = 0.f;
        for (int c = 0; c < CA; c++) {
            float v = x[((size_t)b * CA + c) * T + t];
            s += v * v;
        }
        out[i] = s;
    }
}

// ---------------------------------------------------------------------------
// attention epilogue: one block per (t1, b) row of 200 scores
// ---------------------------------------------------------------------------
__device__ __forceinline__ float wave_max(float v) {
#pragma unroll
    for (int o = 1; o < 64; o <<= 1) v = fmaxf(v, __shfl_xor(v, o, 64));
    return v;
}
__device__ __forceinline__ float wave_sum(float v) {
#pragma unroll
    for (int o = 1; o < 64; o <<= 1) v += __shfl_xor(v, o, 64);
    return v;
}
__device__ __forceinline__ float block_max(float v, float* red) {
    v = wave_max(v);
    __syncthreads();
    if ((threadIdx.x & 63) == 0) red[threadIdx.x >> 6] = v;
    __syncthreads();
    return fmaxf(fmaxf(red[0], red[1]), fmaxf(red[2], red[3]));
}
__device__ __forceinline__ float block_sum(float v, float* red) {
    v = wave_sum(v);
    __syncthreads();
    if ((threadIdx.x & 63) == 0) red[threadIdx.x >> 6] = v;
    __syncthreads();
    return red[0] + red[1] + red[2] + red[3];
}

__global__ __launch_bounds__(256) void attn_kernel(const float* __restrict__ q_enc,
                                                   const float* __restrict__ k_enc,
                                                   const float* __restrict__ q2,
                                                   const float* __restrict__ k2,
                                                   const float* __restrict__ prior,
                                                   const int* __restrict__ mask,
                                                   float* __restrict__ out_attn,
                                                   float* __restrict__ out_logp) {
    const int t1 = blockIdx.x, b = blockIdx.y, tid = threadIdx.x;
    __shared__ float QS[CA];
    __shared__ float red[4];
    if (tid < CA) QS[tid] = q_enc[((size_t)b * CA + tid) * T1 + t1];
    __syncthreads();
    float s = -INFINITY;
    if (tid < T2) {
        float dot = 0.f;
#pragma unroll 8
        for (int c = 0; c < CA; c++) dot += QS[c] * k_enc[((size_t)b * CA + c) * T2 + tid];
        s = -TEMP_F * (q2[b * T1 + t1] + k2[b * T2 + tid] - 2.f * dot);
    }
    float m = block_max(s, red);
    float e = (tid < T2) ? __expf(s - m) : 0.f;
    float Z = block_sum(e, red);
    float lp = 0.f;
    if (tid < T2) {
        float pr = prior[((size_t)b * T1 + t1) * T2 + tid];
        lp = (s - m - __logf(Z)) + __logf(pr + 1e-8f);
    }
    float ms = (tid < T2 && mask[b * T2 + tid] != 0) ? lp : -INFINITY;
    float m2 = block_max(ms, red);
    float e2 = (tid < T2) ? __expf(ms - m2) : 0.f;
    float Z2 = block_sum(e2, red);
    if (tid < T2) {
        size_t o = ((size_t)b * T1 + t1) * T2 + tid;
        out_attn[o] = e2 / Z2;
        out_logp[o] = lp;
    }
}

// ---------------------------------------------------------------------------
extern "C" void kernel_launch(void* const* d_in, const int* in_sizes, int n_in,
                              void* d_out, int out_size, void* d_ws, size_t ws_size,
                              hipStream_t stream) {
    const float* queries = (const float*)d_in[0];
    const float* keys    = (const float*)d_in[1];
    const int*   mask    = (const int*)d_in[2];
    const float* prior   = (const float*)d_in[3];
    const float* g       = (const float*)d_in[4];
    const float* wk1 = (const float*)d_in[5];
    const float* bk1 = (const float*)d_in[6];
    const float* wk2 = (const float*)d_in[7];
    const float* bk2 = (const float*)d_in[8];
    const float* wq1 = (const float*)d_in[9];
    const float* bq1 = (const float*)d_in[10];
    const float* wq2 = (const float*)d_in[11];
    const float* bq2 = (const float*)d_in[12];
    const float* wq3 = (const float*)d_in[13];
    const float* bq3 = (const float*)d_in[14];
    const float* w_kspk = (const float*)d_in[15];
    const float* b_kspk = (const float*)d_in[16];
    const float* w_qspk = (const float*)d_in[17];
    const float* b_qspk = (const float*)d_in[18];

    float* ws = (float*)d_ws;
    // workspace layout (floats), with buffer reuse:
    float* kspk  = ws;                        // 16*512          = 8192
    float* qspk  = ws + 8192;                 // 16*80           = 1280
    float* xk    = ws + 9472;                 // 16*512*200      = 1638400   (later reused as q_enc)
    float* xq    = ws + 1647872;              // 16*80*1000      = 1280000   (later reused as qh2)
    float* k_enc = ws + 2927872;              // 16*80*200       = 256000
    float* q2    = ws + 3183872;              // 16*1000         = 16000
    float* k2    = ws + 3199872;              // 16*200          = 3200      -> 3203072 floats (12.8 MB)
    // hidden conv layers live in d_out (25.6 MB; final attn kernel overwrites it last):
    float* kh1   = (float*)d_out;             // 16*1024*200     = 3276800   (12.9 MB) (reused as qh1)
    float* q_enc = xk;
    float* qh2   = xq;
    float* qh1   = kh1;

    // 1. speaker projections
    spk_kernel<<<dim3((NB * (CT + CS) + 255) / 256), dim3(256), 0, stream>>>(
        g, w_kspk, b_kspk, w_qspk, b_qspk, kspk, qspk);
    // 2. x = input + spk
    addspk_kernel<CT, T2><<<dim3(NB * CT * T2 / 256), dim3(256), 0, stream>>>(keys, kspk, xk);
    addspk_kernel<CS, T1><<<dim3(NB * CS * T1 / 256), dim3(256), 0, stream>>>(queries, qspk, xq);
    // 3. key path: conv3(512->1024)+relu, then 1x1(1024->80)
    conv3_relu_kernel<CT, T2><<<dim3(1, C2T / 16, NB), dim3(256), 0, stream>>>(xk, wk1, bk1, kh1);
    conv1x1_kernel<C2T, T2, false, 1><<<dim3(CA, NB), dim3(256), 0, stream>>>(kh1, wk2, bk2, k_enc);
    // 4. query path: conv3(80->160)+relu, 1x1(160->80)+relu, 1x1(80->80)
    conv3_relu_kernel<CS, T1><<<dim3(4, C2S / 16, NB), dim3(256), 0, stream>>>(xq, wq1, bq1, qh1);
    conv1x1_kernel<C2S, T1, true, 4><<<dim3(CS, NB), dim3(256), 0, stream>>>(qh1, wq2, bq2, qh2);
    conv1x1_kernel<CS, T1, false, 4><<<dim3(CA, NB), dim3(256), 0, stream>>>(qh2, wq3, bq3, q_enc);
    // 5. squared norms
    sqsum_kernel<<<dim3((NB * T1 + 255) / 256), dim3(256), 0, stream>>>(q_enc, q2, T1);
    sqsum_kernel<<<dim3((NB * T2 + 255) / 256), dim3(256), 0, stream>>>(k_enc, k2, T2);
    // 6. distances + log_softmax + prior + masked softmax
    float* out_attn = (float*)d_out;
    float* out_logp = out_attn + (size_t)NB * T1 * T2;
    attn_kernel<<<dim3(T1, NB), dim3(256), 0, stream>>>(q_enc, k_enc, q2, k2, prior, mask,
                                                        out_attn, out_logp);
}

// Round 3
// 763.143 us; speedup vs baseline: 1.8128x; 1.8128x over previous
//
#include <hip/hip_runtime.h>
#include <hip/hip_bf16.h>
#include <math.h>

#define NB 16      // batch
#define CS 80      // spec channels
#define T1 1000    // mel frames
#define CT 512     // text channels
#define T2 200     // phonemes
#define CA 80      // attn channels
#define GD 256     // speaker dim
#define C2T 1024   // 2*Ct
#define C2S 160    // 2*Cs
#define TEMP_F 0.0005f

typedef __attribute__((ext_vector_type(8))) short short8;
typedef __attribute__((ext_vector_type(4))) float floatx4;

// fp32 -> bf16 bits, round-to-nearest-even
__device__ __forceinline__ short f2bf(float x) {
    unsigned u = __builtin_bit_cast(unsigned, x);
    unsigned r = (u + 0x7fffu + ((u >> 16) & 1u)) >> 16;
    return (short)r;
}

// ---------------------------------------------------------------------------
// speaker projections: kspk[b][c] = b_kspk[c] + g[b]·w_kspk[c], qspk likewise
// ---------------------------------------------------------------------------
__global__ void spk_kernel(const float* __restrict__ g,
                           const float* __restrict__ w_kspk, const float* __restrict__ b_kspk,
                           const float* __restrict__ w_qspk, const float* __restrict__ b_qspk,
                           float* __restrict__ kspk, float* __restrict__ qspk) {
    int i = blockIdx.x * 256 + threadIdx.x;
    const int NK = NB * CT;               // 8192
    if (i < NK) {
        int b = i >> 9, c = i & 511;
        float s = b_kspk[c];
        for (int j = 0; j < GD; j++) s += g[b * GD + j] * w_kspk[c * GD + j];
        kspk[i] = s;
    } else {
        int i2 = i - NK;
        if (i2 < NB * CS) {
            int b = i2 / CS, c = i2 - b * CS;
            float s = b_qspk[c];
            for (int j = 0; j < GD; j++) s += g[b * GD + j] * w_qspk[c * GD + j];
            qspk[i2] = s;
        }
    }
}

// ---------------------------------------------------------------------------
// x[b][c][t] = in[b][c][t] + spk[b][c]
// ---------------------------------------------------------------------------
template <int C, int T>
__global__ void addspk_kernel(const float* __restrict__ in, const float* __restrict__ spk,
                              float* __restrict__ outx) {
    int i = blockIdx.x * 256 + threadIdx.x;
    if (i < NB * C * T) {
        int ct = i / T;                 // == b*C + c
        outx[i] = in[i] + spk[ct];
    }
}

// ---------------------------------------------------------------------------
// MFMA conv-as-GEMM: out[b][co][t] = act(bias[co] + sum_{ci,k} w[co][ci][k] * x[b][ci][t+k-PAD])
// Block tile: 64 co x 128 t, 4 waves, each wave 32 co x 64 t (2 A-frags x 4 B-frags,
// 8 accumulators). K chunked by 32 ci; fp32->bf16 conversion during LDS staging.
// im2col via halo rows in the X tile. mfma_f32_16x16x32_bf16:
//   A frag: lane holds A[m=lane&15][k=(lane>>4)*8+j]   (m -> co, k -> ci)
//   B frag: lane holds B[k=(lane>>4)*8+j][n=lane&15]   (n -> t)
//   D frag: lane reg r -> row(co)=(lane>>4)*4+r, col(t)=lane&15
// ---------------------------------------------------------------------------
template <int CIN, int COUT, int T, int KW, bool RELU>
__global__ __launch_bounds__(256) void conv_mfma(const float* __restrict__ x,
                                                 const float* __restrict__ w,
                                                 const float* __restrict__ bias,
                                                 float* __restrict__ out) {
    constexpr int PAD = KW / 2;
    constexpr int TH = 128 + KW - 1;        // X tile rows incl halo
    constexpr int NKC = (CIN + 31) / 32;    // K chunks
    constexpr int STR = 40;                 // shorts per LDS row (80 B: 16B-aligned, 2-way banks)
    __shared__ short Xs[TH * STR];          // Xs[t'][ci']   t' = global t - (t_blk0 - PAD)
    __shared__ short Ws[KW * 64 * STR];     // Ws[k][co'][ci']

    const int t_blk0 = blockIdx.x * 128;
    const int co_blk0 = blockIdx.y * 64;
    const int b = blockIdx.z;
    const int tid = threadIdx.x;
    const int wave = tid >> 6, lane = tid & 63;
    const int quad = lane >> 4, l16 = lane & 15;
    const int wco = (wave & 1) * 32;        // wave's co offset within the 64
    const int wt = (wave >> 1) * 64;        // wave's t offset within the 128

    const float* xb = x + (size_t)b * CIN * T;
    floatx4 acc[2][4];
#pragma unroll
    for (int h = 0; h < 2; h++)
#pragma unroll
        for (int tt = 0; tt < 4; tt++) acc[h][tt] = (floatx4){0.f, 0.f, 0.f, 0.f};

    for (int kc = 0; kc < NKC; kc++) {
        const int ci0 = kc * 32;
        __syncthreads();   // protect LDS from previous chunk's readers
        // stage X chunk (32 ci x TH t), transposed to [t'][ci']
        for (int idx = tid; idx < 32 * TH; idx += 256) {
            int ci = idx / TH, tt = idx - ci * TH;
            int gt = t_blk0 - PAD + tt;
            float v = 0.f;
            if ((unsigned)gt < (unsigned)T && ci0 + ci < CIN) v = xb[(ci0 + ci) * T + gt];
            Xs[tt * STR + ci] = f2bf(v);
        }
        // stage W chunk (64 co x 32 ci x KW), to [k][co'][ci']
        for (int idx = tid; idx < 64 * 32 * KW; idx += 256) {
            int co = idx / (32 * KW), r = idx - co * (32 * KW);
            int ci = r / KW, k = r - ci * KW;
            float v = 0.f;
            if (co_blk0 + co < COUT && ci0 + ci < CIN)
                v = w[(size_t)(co_blk0 + co) * (CIN * KW) + (ci0 + ci) * KW + k];
            Ws[(k * 64 + co) * STR + ci] = f2bf(v);
        }
        __syncthreads();
#pragma unroll
        for (int k = 0; k < KW; k++) {
            short8 a0 = *(const short8*)&Ws[(k * 64 + wco + l16) * STR + quad * 8];
            short8 a1 = *(const short8*)&Ws[(k * 64 + wco + 16 + l16) * STR + quad * 8];
#pragma unroll
            for (int tt = 0; tt < 4; tt++) {
                short8 bf = *(const short8*)&Xs[(wt + tt * 16 + l16 + k) * STR + quad * 8];
                acc[0][tt] = __builtin_amdgcn_mfma_f32_16x16x32_bf16(a0, bf, acc[0][tt], 0, 0, 0);
                acc[1][tt] = __builtin_amdgcn_mfma_f32_16x16x32_bf16(a1, bf, acc[1][tt], 0, 0, 0);
            }
        }
    }
    // epilogue: D layout row(co) = quad*4 + reg, col(t) = l16
#pragma unroll
    for (int h = 0; h < 2; h++) {
        int cobase = co_blk0 + wco + h * 16 + quad * 4;
#pragma unroll
        for (int r = 0; r < 4; r++) {
            int co = cobase + r;
            if (co < COUT) {
                float bv = bias[co];
#pragma unroll
                for (int tt = 0; tt < 4; tt++) {
                    int t = t_blk0 + wt + tt * 16 + l16;
                    if (t < T) {
                        float v = acc[h][tt][r] + bv;
                        out[((size_t)b * COUT + co) * T + t] = RELU ? fmaxf(v, 0.f) : v;
                    }
                }
            }
        }
    }
}

// ---------------------------------------------------------------------------
// out[b][t] = sum_c x[b][c][t]^2
// ---------------------------------------------------------------------------
__global__ void sqsum_kernel(const float* __restrict__ x, float* __restrict__ out, int T) {
    int i = blockIdx.x * 256 + threadIdx.x;
    if (i < NB * T) {
        int b = i / T, t = i - b * T;
        float s = 0.f;
        for (int c = 0; c < CA; c++) {
            float v = x[((size_t)b * CA + c) * T + t];
            s += v * v;
        }
        out[i] = s;
    }
}

// ---------------------------------------------------------------------------
// attention epilogue: one block per (t1, b) row of 200 scores
// ---------------------------------------------------------------------------
__device__ __forceinline__ float wave_max(float v) {
#pragma unroll
    for (int o = 1; o < 64; o <<= 1) v = fmaxf(v, __shfl_xor(v, o, 64));
    return v;
}
__device__ __forceinline__ float wave_sum(float v) {
#pragma unroll
    for (int o = 1; o < 64; o <<= 1) v += __shfl_xor(v, o, 64);
    return v;
}
__device__ __forceinline__ float block_max(float v, float* red) {
    v = wave_max(v);
    __syncthreads();
    if ((threadIdx.x & 63) == 0) red[threadIdx.x >> 6] = v;
    __syncthreads();
    return fmaxf(fmaxf(red[0], red[1]), fmaxf(red[2], red[3]));
}
__device__ __forceinline__ float block_sum(float v, float* red) {
    v = wave_sum(v);
    __syncthreads();
    if ((threadIdx.x & 63) == 0) red[threadIdx.x >> 6] = v;
    __syncthreads();
    return red[0] + red[1] + red[2] + red[3];
}

__global__ __launch_bounds__(256) void attn_kernel(const float* __restrict__ q_enc,
                                                   const float* __restrict__ k_enc,
                                                   const float* __restrict__ q2,
                                                   const float* __restrict__ k2,
                                                   const float* __restrict__ prior,
                                                   const int* __restrict__ mask,
                                                   float* __restrict__ out_attn,
                                                   float* __restrict__ out_logp) {
    const int t1 = blockIdx.x, b = blockIdx.y, tid = threadIdx.x;
    __shared__ float QS[CA];
    __shared__ float red[4];
    if (tid < CA) QS[tid] = q_enc[((size_t)b * CA + tid) * T1 + t1];
    __syncthreads();
    float s = -INFINITY;
    if (tid < T2) {
        float dot = 0.f;
#pragma unroll 8
        for (int c = 0; c < CA; c++) dot += QS[c] * k_enc[((size_t)b * CA + c) * T2 + tid];
        s = -TEMP_F * (q2[b * T1 + t1] + k2[b * T2 + tid] - 2.f * dot);
    }
    float m = block_max(s, red);
    float e = (tid < T2) ? __expf(s - m) : 0.f;
    float Z = block_sum(e, red);
    float lp = 0.f;
    if (tid < T2) {
        float pr = prior[((size_t)b * T1 + t1) * T2 + tid];
        lp = (s - m - __logf(Z)) + __logf(pr + 1e-8f);
    }
    float ms = (tid < T2 && mask[b * T2 + tid] != 0) ? lp : -INFINITY;
    float m2 = block_max(ms, red);
    float e2 = (tid < T2) ? __expf(ms - m2) : 0.f;
    float Z2 = block_sum(e2, red);
    if (tid < T2) {
        size_t o = ((size_t)b * T1 + t1) * T2 + tid;
        out_attn[o] = e2 / Z2;
        out_logp[o] = lp;
    }
}

// ---------------------------------------------------------------------------
extern "C" void kernel_launch(void* const* d_in, const int* in_sizes, int n_in,
                              void* d_out, int out_size, void* d_ws, size_t ws_size,
                              hipStream_t stream) {
    const float* queries = (const float*)d_in[0];
    const float* keys    = (const float*)d_in[1];
    const int*   mask    = (const int*)d_in[2];
    const float* prior   = (const float*)d_in[3];
    const float* g       = (const float*)d_in[4];
    const float* wk1 = (const float*)d_in[5];
    const float* bk1 = (const float*)d_in[6];
    const float* wk2 = (const float*)d_in[7];
    const float* bk2 = (const float*)d_in[8];
    const float* wq1 = (const float*)d_in[9];
    const float* bq1 = (const float*)d_in[10];
    const float* wq2 = (const float*)d_in[11];
    const float* bq2 = (const float*)d_in[12];
    const float* wq3 = (const float*)d_in[13];
    const float* bq3 = (const float*)d_in[14];
    const float* w_kspk = (const float*)d_in[15];
    const float* b_kspk = (const float*)d_in[16];
    const float* w_qspk = (const float*)d_in[17];
    const float* b_qspk = (const float*)d_in[18];

    float* ws = (float*)d_ws;
    // workspace layout (floats), with buffer reuse:
    float* kspk  = ws;                        // 16*512          = 8192
    float* qspk  = ws + 8192;                 // 16*80           = 1280
    float* xk    = ws + 9472;                 // 16*512*200      = 1638400   (later reused as q_enc)
    float* xq    = ws + 1647872;              // 16*80*1000      = 1280000   (later reused as qh2)
    float* k_enc = ws + 2927872;              // 16*80*200       = 256000
    float* q2    = ws + 3183872;              // 16*1000         = 16000
    float* k2    = ws + 3199872;              // 16*200          = 3200      -> 3203072 floats (12.8 MB)
    // hidden conv layers live in d_out (25.6 MB; final attn kernel overwrites it last):
    float* kh1   = (float*)d_out;             // 16*1024*200     = 3276800   (13.1 MB) (reused as qh1)
    float* q_enc = xk;
    float* qh2   = xq;
    float* qh1   = kh1;

    // 1. speaker projections
    spk_kernel<<<dim3((NB * (CT + CS) + 255) / 256), dim3(256), 0, stream>>>(
        g, w_kspk, b_kspk, w_qspk, b_qspk, kspk, qspk);
    // 2. x = input + spk
    addspk_kernel<CT, T2><<<dim3(NB * CT * T2 / 256), dim3(256), 0, stream>>>(keys, kspk, xk);
    addspk_kernel<CS, T1><<<dim3(NB * CS * T1 / 256), dim3(256), 0, stream>>>(queries, qspk, xq);
    // 3. key path: conv3(512->1024)+relu, then 1x1(1024->80)
    conv_mfma<CT, C2T, T2, 3, true><<<dim3(2, 16, NB), dim3(256), 0, stream>>>(xk, wk1, bk1, kh1);
    conv_mfma<C2T, CA, T2, 1, false><<<dim3(2, 2, NB), dim3(256), 0, stream>>>(kh1, wk2, bk2, k_enc);
    // 4. query path: conv3(80->160)+relu, 1x1(160->80)+relu, 1x1(80->80)
    conv_mfma<CS, C2S, T1, 3, true><<<dim3(8, 3, NB), dim3(256), 0, stream>>>(xq, wq1, bq1, qh1);
    conv_mfma<C2S, CS, T1, 1, true><<<dim3(8, 2, NB), dim3(256), 0, stream>>>(qh1, wq2, bq2, qh2);
    conv_mfma<CS, CA, T1, 1, false><<<dim3(8, 2, NB), dim3(256), 0, stream>>>(qh2, wq3, bq3, q_enc);
    // 5. squared norms
    sqsum_kernel<<<dim3((NB * T1 + 255) / 256), dim3(256), 0, stream>>>(q_enc, q2, T1);
    sqsum_kernel<<<dim3((NB * T2 + 255) / 256), dim3(256), 0, stream>>>(k_enc, k2, T2);
    // 6. distances + log_softmax + prior + masked softmax
    float* out_attn = (float*)d_out;
    float* out_logp = out_attn + (size_t)NB * T1 * T2;
    attn_kernel<<<dim3(T1, NB), dim3(256), 0, stream>>>(q_enc, k_enc, q2, k2, prior, mask,
                                                        out_attn, out_logp);
}

// Round 4
// 315.639 us; speedup vs baseline: 4.3829x; 2.4178x over previous
//
#include <hip/hip_runtime.h>
#include <hip/hip_bf16.h>
#include <math.h>

#define NB 16      // batch
#define CS 80      // spec channels
#define T1 1000    // mel frames
#define CT 512     // text channels
#define T2 200     // phonemes
#define CA 80      // attn channels
#define GD 256     // speaker dim
#define C2T 1024   // 2*Ct
#define C2S 160    // 2*Cs
#define TEMP_F 0.0005f

typedef __attribute__((ext_vector_type(8))) short short8;
typedef __attribute__((ext_vector_type(4))) float floatx4;

// fp32 -> bf16 bits, round-to-nearest-even
__device__ __forceinline__ short f2bf(float x) {
    unsigned u = __builtin_bit_cast(unsigned, x);
    unsigned r = (u + 0x7fffu + ((u >> 16) & 1u)) >> 16;
    return (short)r;
}
__device__ __forceinline__ float bf2f(short s) {
    unsigned u = ((unsigned)(unsigned short)s) << 16;
    return __builtin_bit_cast(float, u);
}

// ---------------------------------------------------------------------------
// speaker projections: kspk[b][c] = b_kspk[c] + g[b]·w_kspk[c], qspk likewise
// ---------------------------------------------------------------------------
__global__ void spk_kernel(const float* __restrict__ g,
                           const float* __restrict__ w_kspk, const float* __restrict__ b_kspk,
                           const float* __restrict__ w_qspk, const float* __restrict__ b_qspk,
                           float* __restrict__ kspk, float* __restrict__ qspk) {
    int i = blockIdx.x * 256 + threadIdx.x;
    const int NK = NB * CT;               // 8192
    if (i < NK) {
        int b = i >> 9, c = i & 511;
        float s = b_kspk[c];
        for (int j = 0; j < GD; j++) s += g[b * GD + j] * w_kspk[c * GD + j];
        kspk[i] = s;
    } else {
        int i2 = i - NK;
        if (i2 < NB * CS) {
            int b = i2 / CS, c = i2 - b * CS;
            float s = b_qspk[c];
            for (int j = 0; j < GD; j++) s += g[b * GD + j] * w_qspk[c * GD + j];
            qspk[i2] = s;
        }
    }
}

// ---------------------------------------------------------------------------
// fused speaker-add + transpose: in fp32 [b][C][T] + spk[b][C] -> out bf16 [b][T][C]
// 32c x 64t LDS tile
// ---------------------------------------------------------------------------
template <int C, int T>
__global__ __launch_bounds__(256) void addspkT_kernel(const float* __restrict__ in,
                                                      const float* __restrict__ spk,
                                                      short* __restrict__ outT) {
    __shared__ float S[32][65];
    const int t0 = blockIdx.x * 64, c0 = blockIdx.y * 32, b = blockIdx.z;
    const int tid = threadIdx.x;
    for (int i = tid; i < 32 * 64; i += 256) {
        int cl = i >> 6, tl = i & 63;
        int gc = c0 + cl, gt = t0 + tl;
        float v = 0.f;
        if (gc < C && gt < T) v = in[((size_t)b * C + gc) * T + gt] + spk[b * C + gc];
        S[cl][tl] = v;
    }
    __syncthreads();
    for (int i = tid; i < 64 * 32; i += 256) {
        int tl = i >> 5, cl = i & 31;
        int gt = t0 + tl, gc = c0 + cl;
        if (gc < C && gt < T) outT[((size_t)b * T + gt) * C + gc] = f2bf(S[cl][tl]);
    }
}

// ---------------------------------------------------------------------------
// weight conversion: w fp32 [COUT][CIN][KW] -> wT bf16 [KW][COUT][CIN]
// ---------------------------------------------------------------------------
template <int COUT, int CIN, int KW>
__global__ void convertW_kernel(const float* __restrict__ w, short* __restrict__ wT) {
    int i = blockIdx.x * 256 + threadIdx.x;
    if (i < KW * COUT * CIN) {
        int k = i / (COUT * CIN), r = i - k * (COUT * CIN);
        int co = r / CIN, ci = r - co * CIN;
        wT[i] = f2bf(w[((size_t)co * CIN + ci) * KW + k]);
    }
}

// ---------------------------------------------------------------------------
// MFMA conv-as-GEMM, bf16 T-layout in and out.
//   xT  bf16 [b][T][CIN], wT bf16 [KW][COUT][CIN], bias fp32, outT bf16 [b][T][COUT]
// Block tile COT co x TT t; 4 waves as (COT/WCO) x (TT/WT); K chunked by CICH ci.
// LDS rows padded to PITCH = CICH+8 shorts (2-way-only b128 bank pattern).
// mfma_f32_16x16x32_bf16 conventions (validated round 3):
//   A lane: m=l16 (co), k=quad*8+j;  B lane: n=l16 (t), k=quad*8+j
//   D lane reg r: row(co)=quad*4+r, col(t)=l16
// ---------------------------------------------------------------------------
template <int CIN, int COUT, int T, int KW, bool RELU,
          int COT, int TT, int WCO, int WT, int CICH>
__global__ __launch_bounds__(256) void conv_mfma(const short* __restrict__ xT,
                                                 const short* __restrict__ wT,
                                                 const float* __restrict__ bias,
                                                 short* __restrict__ outT) {
    constexpr int PAD = KW / 2;
    constexpr int XROWS = TT + KW - 1;
    constexpr int PITCH = CICH + 8;
    constexpr int NPC = CICH / 8;            // 16B pieces per row
    constexpr int NKC = (CIN + CICH - 1) / CICH;
    constexpr int MT = WCO / 16, NT = WT / 16;
    constexpr int NWCO = COT / WCO;
    __shared__ short Xs[XROWS * PITCH];
    __shared__ short Ws[KW * COT * PITCH];

    const int t0 = blockIdx.x * TT, co0 = blockIdx.y * COT, b = blockIdx.z;
    const int tid = threadIdx.x;
    const int wave = tid >> 6, lane = tid & 63;
    const int quad = lane >> 4, l16 = lane & 15;
    const int wco_off = (wave % NWCO) * WCO;
    const int wt_off = (wave / NWCO) * WT;

    floatx4 acc[MT][NT];
#pragma unroll
    for (int mi = 0; mi < MT; mi++)
#pragma unroll
        for (int ni = 0; ni < NT; ni++) acc[mi][ni] = (floatx4){0.f, 0.f, 0.f, 0.f};

    for (int kc = 0; kc < NKC; kc++) {
        const int ci0 = kc * CICH;
        if (kc) __syncthreads();
        // stage X tile rows [t0-PAD .. t0+TT-1+PAD], ci slice [ci0, ci0+CICH)
        for (int i = tid; i < XROWS * NPC; i += 256) {
            int r = i / NPC, p = i - r * NPC;
            int t = t0 + r - PAD, ci = ci0 + p * 8;
            uint4 v = {0u, 0u, 0u, 0u};
            if ((unsigned)t < (unsigned)T && ci + 8 <= CIN)
                v = *(const uint4*)(xT + ((size_t)b * T + t) * CIN + ci);
            *(uint4*)(Xs + r * PITCH + p * 8) = v;
        }
        // stage W tile [KW][COT][CICH]
        for (int i = tid; i < KW * COT * NPC; i += 256) {
            int rr = i / NPC, p = i - rr * NPC;
            int k = rr / COT, col = rr - k * COT;
            int co = co0 + col, ci = ci0 + p * 8;
            uint4 v = {0u, 0u, 0u, 0u};
            if (co < COUT && ci + 8 <= CIN)
                v = *(const uint4*)(wT + ((size_t)k * COUT + co) * CIN + ci);
            *(uint4*)(Ws + rr * PITCH + p * 8) = v;
        }
        __syncthreads();
#pragma unroll
        for (int k = 0; k < KW; k++) {
#pragma unroll
            for (int kk = 0; kk < CICH / 32; kk++) {
                short8 a[MT];
#pragma unroll
                for (int mi = 0; mi < MT; mi++)
                    a[mi] = *(const short8*)(Ws + (k * COT + wco_off + mi * 16 + l16) * PITCH +
                                             kk * 32 + quad * 8);
#pragma unroll
                for (int ni = 0; ni < NT; ni++) {
                    short8 bb = *(const short8*)(Xs + (wt_off + ni * 16 + l16 + k) * PITCH +
                                                 kk * 32 + quad * 8);
#pragma unroll
                    for (int mi = 0; mi < MT; mi++)
                        acc[mi][ni] = __builtin_amdgcn_mfma_f32_16x16x32_bf16(a[mi], bb,
                                                                              acc[mi][ni], 0, 0, 0);
                }
            }
        }
    }
    // epilogue: pack 4 consecutive co (r=0..3) into one 8B store
#pragma unroll
    for (int mi = 0; mi < MT; mi++) {
        int cb = co0 + wco_off + mi * 16 + quad * 4;
        if (cb < COUT) {
            float4 bv = *(const float4*)(bias + cb);
#pragma unroll
            for (int ni = 0; ni < NT; ni++) {
                int t = t0 + wt_off + ni * 16 + l16;
                if (t < T) {
                    float v0 = acc[mi][ni][0] + bv.x, v1 = acc[mi][ni][1] + bv.y;
                    float v2 = acc[mi][ni][2] + bv.z, v3 = acc[mi][ni][3] + bv.w;
                    if (RELU) {
                        v0 = fmaxf(v0, 0.f); v1 = fmaxf(v1, 0.f);
                        v2 = fmaxf(v2, 0.f); v3 = fmaxf(v3, 0.f);
                    }
                    ushort4 o;
                    o.x = (unsigned short)f2bf(v0); o.y = (unsigned short)f2bf(v1);
                    o.z = (unsigned short)f2bf(v2); o.w = (unsigned short)f2bf(v3);
                    *(ushort4*)(outT + ((size_t)b * T + t) * COUT + cb) = o;
                }
            }
        }
    }
}

// ---------------------------------------------------------------------------
// attention: block = (64 t1) x b.  QK^T via MFMA from LDS-staged bf16 tiles,
// q^2 dropped (row-constant cancels in log_softmax), k^2 computed in-block.
// ---------------------------------------------------------------------------
__device__ __forceinline__ float rmax16(float v) {
#pragma unroll
    for (int o = 1; o < 16; o <<= 1) v = fmaxf(v, __shfl_xor(v, o, 64));
    return v;
}
__device__ __forceinline__ float rsum16(float v) {
#pragma unroll
    for (int o = 1; o < 16; o <<= 1) v += __shfl_xor(v, o, 64);
    return v;
}

__global__ __launch_bounds__(256) void attn_kernel(const short* __restrict__ q_encT,
                                                   const short* __restrict__ k_encT,
                                                   const float* __restrict__ prior,
                                                   const int* __restrict__ mask,
                                                   float* __restrict__ out_attn,
                                                   float* __restrict__ out_logp) {
    constexpr int T2R = 208, PITCH = 104, NPC = 12;   // 13 n-tiles, 96 ci padded
    __shared__ short Kt[T2R * PITCH];
    __shared__ short Qs[64 * PITCH];
    __shared__ float k2s[T2R];
    __shared__ int msk[T2R];
    const int t10 = blockIdx.x * 64, b = blockIdx.y;
    const int tid = threadIdx.x;
    const int wave = tid >> 6, lane = tid & 63;
    const int quad = lane >> 4, l16 = lane & 15;

    // stage K tile [208][96pad]
    for (int i = tid; i < T2R * NPC; i += 256) {
        int r = i / NPC, p = i - r * NPC;
        uint4 v = {0u, 0u, 0u, 0u};
        if (r < T2 && p < 10) v = *(const uint4*)(k_encT + ((size_t)b * T2 + r) * CA + p * 8);
        *(uint4*)(Kt + r * PITCH + p * 8) = v;
    }
    // stage Q tile [64][96pad]
    for (int i = tid; i < 64 * NPC; i += 256) {
        int r = i / NPC, p = i - r * NPC;
        int t1 = t10 + r;
        uint4 v = {0u, 0u, 0u, 0u};
        if (t1 < T1 && p < 10) v = *(const uint4*)(q_encT + ((size_t)b * T1 + t1) * CA + p * 8);
        *(uint4*)(Qs + r * PITCH + p * 8) = v;
    }
    if (tid < T2R) msk[tid] = (tid < T2) ? mask[b * T2 + tid] : 0;
    __syncthreads();
    // k2 from staged tile
    for (int r = tid; r < T2R; r += 256) {
        float s = 0.f;
        for (int p = 0; p < NPC; p++) {
            short8 v = *(const short8*)(Kt + r * PITCH + p * 8);
#pragma unroll
            for (int j = 0; j < 8; j++) { float f = bf2f(v[j]); s += f * f; }
        }
        k2s[r] = s;
    }
    __syncthreads();

    // QK^T: wave w owns t1 rows [w*16, w*16+16)
    floatx4 acc[13];
#pragma unroll
    for (int n = 0; n < 13; n++) acc[n] = (floatx4){0.f, 0.f, 0.f, 0.f};
#pragma unroll
    for (int kk = 0; kk < 3; kk++) {
        short8 a = *(const short8*)(Qs + (wave * 16 + l16) * PITCH + kk * 32 + quad * 8);
#pragma unroll
        for (int n = 0; n < 13; n++) {
            short8 bb = *(const short8*)(Kt + (n * 16 + l16) * PITCH + kk * 32 + quad * 8);
            acc[n] = __builtin_amdgcn_mfma_f32_16x16x32_bf16(a, bb, acc[n], 0, 0, 0);
        }
    }

    // epilogue: lane owns rows t1 = t10 + wave*16 + quad*4 + r (r=0..3), cols t2 = n*16+l16
#pragma unroll
    for (int r = 0; r < 4; r++) {
        int t1 = t10 + wave * 16 + quad * 4 + r;
        bool t1ok = t1 < T1;
        float s[13];
        float mx = -INFINITY;
#pragma unroll
        for (int n = 0; n < 13; n++) {
            int t2 = n * 16 + l16;
            float sv = -INFINITY;
            if (t2 < T2) sv = -TEMP_F * (k2s[t2] - 2.f * acc[n][r]);
            s[n] = sv;
            mx = fmaxf(mx, sv);
        }
        float m = rmax16(mx);
        float sume = 0.f;
#pragma unroll
        for (int n = 0; n < 13; n++) sume += (s[n] == -INFINITY) ? 0.f : __expf(s[n] - m);
        float logZ = __logf(rsum16(sume));
        float mx2 = -INFINITY;
#pragma unroll
        for (int n = 0; n < 13; n++) {
            int t2 = n * 16 + l16;
            float pr = 1.f;
            if (t1ok && t2 < T2) pr = prior[((size_t)b * T1 + t1) * T2 + t2];
            float lp = (t2 < T2) ? (s[n] - m - logZ + __logf(pr + 1e-8f)) : -INFINITY;
            s[n] = lp;                                  // s[] now holds logprob
            float ms = (t2 < T2 && msk[t2] != 0) ? lp : -INFINITY;
            mx2 = fmaxf(mx2, ms);
        }
        float m2 = rmax16(mx2);
        float sume2 = 0.f;
        float e2v[13];
#pragma unroll
        for (int n = 0; n < 13; n++) {
            int t2 = n * 16 + l16;
            float ms = (t2 < T2 && msk[t2] != 0) ? s[n] : -INFINITY;
            float e = (ms == -INFINITY) ? 0.f : __expf(ms - m2);
            e2v[n] = e;
            sume2 += e;
        }
        float Z2 = rsum16(sume2);
        if (t1ok) {
#pragma unroll
            for (int n = 0; n < 13; n++) {
                int t2 = n * 16 + l16;
                if (t2 < T2) {
                    size_t o = ((size_t)b * T1 + t1) * T2 + t2;
                    out_attn[o] = e2v[n] / Z2;
                    out_logp[o] = s[n];
                }
            }
        }
    }
}

// ---------------------------------------------------------------------------
extern "C" void kernel_launch(void* const* d_in, const int* in_sizes, int n_in,
                              void* d_out, int out_size, void* d_ws, size_t ws_size,
                              hipStream_t stream) {
    const float* queries = (const float*)d_in[0];
    const float* keys    = (const float*)d_in[1];
    const int*   mask    = (const int*)d_in[2];
    const float* prior   = (const float*)d_in[3];
    const float* g       = (const float*)d_in[4];
    const float* wk1 = (const float*)d_in[5];
    const float* bk1 = (const float*)d_in[6];
    const float* wk2 = (const float*)d_in[7];
    const float* bk2 = (const float*)d_in[8];
    const float* wq1 = (const float*)d_in[9];
    const float* bq1 = (const float*)d_in[10];
    const float* wq2 = (const float*)d_in[11];
    const float* bq2 = (const float*)d_in[12];
    const float* wq3 = (const float*)d_in[13];
    const float* bq3 = (const float*)d_in[14];
    const float* w_kspk = (const float*)d_in[15];
    const float* b_kspk = (const float*)d_in[16];
    const float* w_qspk = (const float*)d_in[17];
    const float* b_qspk = (const float*)d_in[18];

    // ---- workspace layout ----
    float* kspk = (float*)d_ws;                      // 8192 fp32
    float* qspk = kspk + 8192;                       // 1280 fp32
    short* wsS  = (short*)d_ws;
    short* xkT   = wsS + 20480;                      // 16x200x512
    short* xqT   = wsS + 1658880;                    // 16x1000x80
    short* wk1b  = wsS + 2938880;                    // 3x1024x512
    short* wk2b  = wsS + 4511744;                    // 1x80x1024
    short* wq1b  = wsS + 4593664;                    // 3x160x80
    short* wq2b  = wsS + 4632064;                    // 1x80x160
    short* wq3b  = wsS + 4644864;                    // 1x80x80
    short* k_encT = wsS + 4651264;                   // 16x200x80
    short* q_encT = wsS + 4907264;                   // 16x1000x80  -> 12.4 MB total
    // hidden layers live in d_out (consumed before attn overwrites it):
    short* doS  = (short*)d_out;
    short* kh1T = doS;                               // 16x200x1024 (6.55 MB)
    short* qh1T = doS + 3276800;                     // 16x1000x160 (5.12 MB)
    short* qh2T = doS + 5836800;                     // 16x1000x80  (2.56 MB)

    // 1. speaker projections + operand prep
    spk_kernel<<<dim3(37), dim3(256), 0, stream>>>(g, w_kspk, b_kspk, w_qspk, b_qspk, kspk, qspk);
    convertW_kernel<C2T, CT, 3><<<dim3((3 * C2T * CT + 255) / 256), dim3(256), 0, stream>>>(wk1, wk1b);
    convertW_kernel<CA, C2T, 1><<<dim3((CA * C2T + 255) / 256), dim3(256), 0, stream>>>(wk2, wk2b);
    convertW_kernel<C2S, CS, 3><<<dim3((3 * C2S * CS + 255) / 256), dim3(256), 0, stream>>>(wq1, wq1b);
    convertW_kernel<CS, C2S, 1><<<dim3((CS * C2S + 255) / 256), dim3(256), 0, stream>>>(wq2, wq2b);
    convertW_kernel<CA, CS, 1><<<dim3((CA * CS + 255) / 256), dim3(256), 0, stream>>>(wq3, wq3b);
    addspkT_kernel<CT, T2><<<dim3(4, 16, NB), dim3(256), 0, stream>>>(keys, kspk, xkT);
    addspkT_kernel<CS, T1><<<dim3(16, 3, NB), dim3(256), 0, stream>>>(queries, qspk, xqT);

    // 2. key path
    conv_mfma<CT, C2T, T2, 3, true, 128, 128, 64, 64, 64>
        <<<dim3(2, 8, NB), dim3(256), 0, stream>>>(xkT, wk1b, bk1, kh1T);
    conv_mfma<C2T, CA, T2, 1, false, 80, 128, 80, 32, 64>
        <<<dim3(2, 1, NB), dim3(256), 0, stream>>>(kh1T, wk2b, bk2, k_encT);
    // 3. query path
    conv_mfma<CS, C2S, T1, 3, true, 64, 128, 64, 32, 96>
        <<<dim3(8, 3, NB), dim3(256), 0, stream>>>(xqT, wq1b, bq1, qh1T);
    conv_mfma<C2S, CS, T1, 1, true, 80, 128, 80, 32, 64>
        <<<dim3(8, 1, NB), dim3(256), 0, stream>>>(qh1T, wq2b, bq2, qh2T);
    conv_mfma<CS, CA, T1, 1, false, 80, 128, 80, 32, 96>
        <<<dim3(8, 1, NB), dim3(256), 0, stream>>>(qh2T, wq3b, bq3, q_encT);
    // 4. attention (q2 cancels in log_softmax; k2 computed in-block)
    float* out_attn = (float*)d_out;
    float* out_logp = out_attn + (size_t)NB * T1 * T2;
    attn_kernel<<<dim3(16, NB), dim3(256), 0, stream>>>(q_encT, k_encT, prior, mask,
                                                        out_attn, out_logp);
}

// Round 5
// 241.300 us; speedup vs baseline: 5.7331x; 1.3081x over previous
//
#include <hip/hip_runtime.h>
#include <hip/hip_bf16.h>
#include <math.h>

#define NB 16      // batch
#define CS 80      // spec channels
#define T1 1000    // mel frames
#define CT 512     // text channels
#define T2 200     // phonemes
#define CA 80      // attn channels
#define GD 256     // speaker dim
#define C2T 1024   // 2*Ct
#define C2S 160    // 2*Cs
#define TEMP_F 0.0005f

typedef __attribute__((ext_vector_type(8))) short short8;
typedef __attribute__((ext_vector_type(4))) float floatx4;

// fp32 -> bf16 bits, round-to-nearest-even
__device__ __forceinline__ short f2bf(float x) {
    unsigned u = __builtin_bit_cast(unsigned, x);
    unsigned r = (u + 0x7fffu + ((u >> 16) & 1u)) >> 16;
    return (short)r;
}
__device__ __forceinline__ float bf2f(short s) {
    unsigned u = ((unsigned)(unsigned short)s) << 16;
    return __builtin_bit_cast(float, u);
}

// ---------------------------------------------------------------------------
// speaker projections, one wave per output channel (coalesced weight rows)
// ---------------------------------------------------------------------------
__global__ __launch_bounds__(256) void spk_kernel(const float* __restrict__ g,
                           const float* __restrict__ w_kspk, const float* __restrict__ b_kspk,
                           const float* __restrict__ w_qspk, const float* __restrict__ b_qspk,
                           float* __restrict__ kspk, float* __restrict__ qspk) {
    int w = (blockIdx.x * 256 + threadIdx.x) >> 6;
    int lane = threadIdx.x & 63;
    const int NK = NB * CT;
    const float* wrow;
    float bias;
    float* dst;
    int b;
    if (w < NK) {
        b = w >> 9;
        int c = w & 511;
        wrow = w_kspk + (size_t)c * GD; bias = b_kspk[c]; dst = kspk + w;
    } else if (w < NK + NB * CS) {
        int i2 = w - NK;
        b = i2 / CS;
        int c = i2 - b * CS;
        wrow = w_qspk + (size_t)c * GD; bias = b_qspk[c]; dst = qspk + i2;
    } else return;
    float s = 0.f;
#pragma unroll
    for (int j = lane; j < GD; j += 64) s += g[b * GD + j] * wrow[j];
#pragma unroll
    for (int o = 1; o < 64; o <<= 1) s += __shfl_xor(s, o, 64);
    if (lane == 0) *dst = s + bias;
}

// ---------------------------------------------------------------------------
// fused speaker-add + transpose: in fp32 [b][C][T] + spk[b][C] -> out bf16 [b][T][C]
// ---------------------------------------------------------------------------
template <int C, int T>
__global__ __launch_bounds__(256) void addspkT_kernel(const float* __restrict__ in,
                                                      const float* __restrict__ spk,
                                                      short* __restrict__ outT) {
    __shared__ float S[32][65];
    const int t0 = blockIdx.x * 64, c0 = blockIdx.y * 32, b = blockIdx.z;
    const int tid = threadIdx.x;
    for (int i = tid; i < 32 * 64; i += 256) {
        int cl = i >> 6, tl = i & 63;
        int gc = c0 + cl, gt = t0 + tl;
        float v = 0.f;
        if (gc < C && gt < T) v = in[((size_t)b * C + gc) * T + gt] + spk[b * C + gc];
        S[cl][tl] = v;
    }
    __syncthreads();
    for (int i = tid; i < 64 * 32; i += 256) {
        int tl = i >> 5, cl = i & 31;
        int gt = t0 + tl, gc = c0 + cl;
        if (gc < C && gt < T) outT[((size_t)b * T + gt) * C + gc] = f2bf(S[cl][tl]);
    }
}

// ---------------------------------------------------------------------------
// weight conversion: w fp32 [COUT][CIN][KW] -> wT bf16 [KW][COUT][CIN]
// ---------------------------------------------------------------------------
template <int COUT, int CIN, int KW>
__global__ void convertW_kernel(const float* __restrict__ w, short* __restrict__ wT) {
    int i = blockIdx.x * 256 + threadIdx.x;
    if (i < KW * COUT * CIN) {
        int k = i / (COUT * CIN), r = i - k * (COUT * CIN);
        int co = r / CIN, ci = r - co * CIN;
        wT[i] = f2bf(w[((size_t)co * CIN + ci) * KW + k]);
    }
}

// ---------------------------------------------------------------------------
// MFMA conv-as-GEMM with halo (k=3), bf16 T-layout in and out.
// mfma_f32_16x16x32_bf16: A lane m=l16,k=quad*8+j; B lane n=l16,k=quad*8+j;
// D lane reg r: row=quad*4+r, col=l16  (validated rounds 3-4)
// ---------------------------------------------------------------------------
template <int CIN, int COUT, int T, int KW, bool RELU,
          int COT, int TT, int WCO, int WT, int CICH>
__global__ __launch_bounds__(256) void conv_mfma(const short* __restrict__ xT,
                                                 const short* __restrict__ wT,
                                                 const float* __restrict__ bias,
                                                 short* __restrict__ outT) {
    constexpr int PAD = KW / 2;
    constexpr int XROWS = TT + KW - 1;
    constexpr int PITCH = CICH + 8;
    constexpr int NPC = CICH / 8;
    constexpr int NKC = (CIN + CICH - 1) / CICH;
    constexpr int MT = WCO / 16, NT = WT / 16;
    constexpr int NWCO = COT / WCO;
    __shared__ short Xs[XROWS * PITCH];
    __shared__ short Ws[KW * COT * PITCH];

    const int t0 = blockIdx.x * TT, co0 = blockIdx.y * COT, b = blockIdx.z;
    const int tid = threadIdx.x;
    const int wave = tid >> 6, lane = tid & 63;
    const int quad = lane >> 4, l16 = lane & 15;
    const int wco_off = (wave % NWCO) * WCO;
    const int wt_off = (wave / NWCO) * WT;

    floatx4 acc[MT][NT];
#pragma unroll
    for (int mi = 0; mi < MT; mi++)
#pragma unroll
        for (int ni = 0; ni < NT; ni++) acc[mi][ni] = (floatx4){0.f, 0.f, 0.f, 0.f};

    for (int kc = 0; kc < NKC; kc++) {
        const int ci0 = kc * CICH;
        if (kc) __syncthreads();
        for (int i = tid; i < XROWS * NPC; i += 256) {
            int r = i / NPC, p = i - r * NPC;
            int t = t0 + r - PAD, ci = ci0 + p * 8;
            uint4 v = {0u, 0u, 0u, 0u};
            if ((unsigned)t < (unsigned)T && ci + 8 <= CIN)
                v = *(const uint4*)(xT + ((size_t)b * T + t) * CIN + ci);
            *(uint4*)(Xs + r * PITCH + p * 8) = v;
        }
        for (int i = tid; i < KW * COT * NPC; i += 256) {
            int rr = i / NPC, p = i - rr * NPC;
            int k = rr / COT, col = rr - k * COT;
            int co = co0 + col, ci = ci0 + p * 8;
            uint4 v = {0u, 0u, 0u, 0u};
            if (co < COUT && ci + 8 <= CIN)
                v = *(const uint4*)(wT + ((size_t)k * COUT + co) * CIN + ci);
            *(uint4*)(Ws + rr * PITCH + p * 8) = v;
        }
        __syncthreads();
#pragma unroll
        for (int k = 0; k < KW; k++) {
#pragma unroll
            for (int kk = 0; kk < CICH / 32; kk++) {
                short8 a[MT];
#pragma unroll
                for (int mi = 0; mi < MT; mi++)
                    a[mi] = *(const short8*)(Ws + (k * COT + wco_off + mi * 16 + l16) * PITCH +
                                             kk * 32 + quad * 8);
#pragma unroll
                for (int ni = 0; ni < NT; ni++) {
                    short8 bb = *(const short8*)(Xs + (wt_off + ni * 16 + l16 + k) * PITCH +
                                                 kk * 32 + quad * 8);
#pragma unroll
                    for (int mi = 0; mi < MT; mi++)
                        acc[mi][ni] = __builtin_amdgcn_mfma_f32_16x16x32_bf16(a[mi], bb,
                                                                              acc[mi][ni], 0, 0, 0);
                }
            }
        }
    }
#pragma unroll
    for (int mi = 0; mi < MT; mi++) {
        int cb = co0 + wco_off + mi * 16 + quad * 4;
        if (cb < COUT) {
            float4 bv = *(const float4*)(bias + cb);
#pragma unroll
            for (int ni = 0; ni < NT; ni++) {
                int t = t0 + wt_off + ni * 16 + l16;
                if (t < T) {
                    float v0 = acc[mi][ni][0] + bv.x, v1 = acc[mi][ni][1] + bv.y;
                    float v2 = acc[mi][ni][2] + bv.z, v3 = acc[mi][ni][3] + bv.w;
                    if (RELU) {
                        v0 = fmaxf(v0, 0.f); v1 = fmaxf(v1, 0.f);
                        v2 = fmaxf(v2, 0.f); v3 = fmaxf(v3, 0.f);
                    }
                    ushort4 o;
                    o.x = (unsigned short)f2bf(v0); o.y = (unsigned short)f2bf(v1);
                    o.z = (unsigned short)f2bf(v2); o.w = (unsigned short)f2bf(v3);
                    *(ushort4*)(outT + ((size_t)b * T + t) * COUT + cb) = o;
                }
            }
        }
    }
}

// ---------------------------------------------------------------------------
// batch-merged 1x1 split-K GEMM: xT [NTOT][K] bf16, w [COUT][K] bf16 ->
// part[s][NTOT][COUT] fp32.  Block = NTILE rows x COUT cols x (K/SPLITK) K.
// ---------------------------------------------------------------------------
template <int K, int COUT, int NTOT, int NTILE, int SPLITK, int CICH>
__global__ __launch_bounds__(256) void gemm_splitk(const short* __restrict__ xT,
                                                   const short* __restrict__ w,
                                                   float* __restrict__ part) {
    constexpr int PITCH = CICH + 8, NPC = CICH / 8;
    constexpr int KSP = K / SPLITK;
    constexpr int NKC = KSP / CICH;
    constexpr int MT = COUT / 16;
    __shared__ short Xs[NTILE * PITCH];
    __shared__ short Ws[COUT * PITCH];
    const int n0 = blockIdx.x * NTILE;
    const int s = blockIdx.y;
    const int tid = threadIdx.x, wave = tid >> 6, lane = tid & 63;
    const int quad = lane >> 4, l16 = lane & 15;
    floatx4 acc[MT];
#pragma unroll
    for (int mi = 0; mi < MT; mi++) acc[mi] = (floatx4){0.f, 0.f, 0.f, 0.f};

    for (int kc = 0; kc < NKC; kc++) {
        const int ci0 = s * KSP + kc * CICH;
        if (kc) __syncthreads();
        for (int i = tid; i < NTILE * NPC; i += 256) {
            int r = i / NPC, p = i - r * NPC;
            *(uint4*)(Xs + r * PITCH + p * 8) =
                *(const uint4*)(xT + (size_t)(n0 + r) * K + ci0 + p * 8);
        }
        for (int i = tid; i < COUT * NPC; i += 256) {
            int r = i / NPC, p = i - r * NPC;
            *(uint4*)(Ws + r * PITCH + p * 8) =
                *(const uint4*)(w + (size_t)r * K + ci0 + p * 8);
        }
        __syncthreads();
#pragma unroll
        for (int kk = 0; kk < CICH / 32; kk++) {
            short8 bb = *(const short8*)(Xs + (wave * 16 + l16) * PITCH + kk * 32 + quad * 8);
#pragma unroll
            for (int mi = 0; mi < MT; mi++) {
                short8 a = *(const short8*)(Ws + (mi * 16 + l16) * PITCH + kk * 32 + quad * 8);
                acc[mi] = __builtin_amdgcn_mfma_f32_16x16x32_bf16(a, bb, acc[mi], 0, 0, 0);
            }
        }
    }
    int n = n0 + wave * 16 + l16;
#pragma unroll
    for (int mi = 0; mi < MT; mi++) {
        int cb = mi * 16 + quad * 4;
        float4 o = {acc[mi][0], acc[mi][1], acc[mi][2], acc[mi][3]};
        *(float4*)(part + ((size_t)s * NTOT + n) * COUT + cb) = o;
    }
}

// combine split-K partials + bias -> bf16 [NTOT][COUT]
template <int COUT, int NTOT, int SPLITK>
__global__ void combine_kernel(const float* __restrict__ part, const float* __restrict__ bias,
                               short* __restrict__ outT) {
    int i = blockIdx.x * 256 + threadIdx.x;
    if (i >= NTOT * (COUT / 4)) return;
    int n = i / (COUT / 4), c4 = i - n * (COUT / 4);
    int co = c4 * 4;
    float4 s = {0.f, 0.f, 0.f, 0.f};
#pragma unroll
    for (int k = 0; k < SPLITK; k++) {
        float4 v = *(const float4*)(part + ((size_t)k * NTOT + n) * COUT + co);
        s.x += v.x; s.y += v.y; s.z += v.z; s.w += v.w;
    }
    float4 b = *(const float4*)(bias + co);
    ushort4 o;
    o.x = (unsigned short)f2bf(s.x + b.x); o.y = (unsigned short)f2bf(s.y + b.y);
    o.z = (unsigned short)f2bf(s.z + b.z); o.w = (unsigned short)f2bf(s.w + b.w);
    *(ushort4*)(outT + (size_t)n * COUT + co) = o;
}

// ---------------------------------------------------------------------------
// fused query conv2(160->80,relu) + conv3(80->80): h1 [16000][160] bf16 ->
// q_encT [16000][80] bf16.  Block = 64 rows; h2 tile bounces through LDS.
// ---------------------------------------------------------------------------
__global__ __launch_bounds__(256) void qconv23_kernel(const short* __restrict__ h1,
                                                      const short* __restrict__ w2,
                                                      const float* __restrict__ b2,
                                                      const short* __restrict__ w3,
                                                      const float* __restrict__ b3,
                                                      short* __restrict__ outT) {
    constexpr int K1 = 160, P1 = 168, NPC1 = 20;
    constexpr int P3 = 104, NPC3 = 12;        // K3 padded 80->96
    __shared__ short Xs[64 * P1];
    __shared__ short W2s[80 * P1];
    __shared__ short W3s[80 * P3];
    __shared__ short Hs[64 * P3];
    const int n0 = blockIdx.x * 64;
    const int tid = threadIdx.x, wave = tid >> 6, lane = tid & 63;
    const int quad = lane >> 4, l16 = lane & 15;

    for (int i = tid; i < 64 * NPC1; i += 256) {
        int r = i / NPC1, p = i - r * NPC1;
        *(uint4*)(Xs + r * P1 + p * 8) = *(const uint4*)(h1 + (size_t)(n0 + r) * K1 + p * 8);
    }
    for (int i = tid; i < 80 * NPC1; i += 256) {
        int r = i / NPC1, p = i - r * NPC1;
        *(uint4*)(W2s + r * P1 + p * 8) = *(const uint4*)(w2 + (size_t)r * K1 + p * 8);
    }
    for (int i = tid; i < 80 * NPC3; i += 256) {
        int r = i / NPC3, p = i - r * NPC3;
        uint4 v = {0u, 0u, 0u, 0u};
        if (p < 10) v = *(const uint4*)(w3 + (size_t)r * 80 + p * 8);
        *(uint4*)(W3s + r * P3 + p * 8) = v;
    }
    if (tid < 128) *(uint4*)(Hs + (tid >> 1) * P3 + 80 + (tid & 1) * 8) = (uint4){0u, 0u, 0u, 0u};
    __syncthreads();

    floatx4 acc[5];
#pragma unroll
    for (int mi = 0; mi < 5; mi++) acc[mi] = (floatx4){0.f, 0.f, 0.f, 0.f};
#pragma unroll
    for (int kk = 0; kk < 5; kk++) {
        short8 bb = *(const short8*)(Xs + (wave * 16 + l16) * P1 + kk * 32 + quad * 8);
#pragma unroll
        for (int mi = 0; mi < 5; mi++) {
            short8 a = *(const short8*)(W2s + (mi * 16 + l16) * P1 + kk * 32 + quad * 8);
            acc[mi] = __builtin_amdgcn_mfma_f32_16x16x32_bf16(a, bb, acc[mi], 0, 0, 0);
        }
    }
#pragma unroll
    for (int mi = 0; mi < 5; mi++) {
        int cb = mi * 16 + quad * 4;
        float4 bv = *(const float4*)(b2 + cb);
        ushort4 o;
        o.x = (unsigned short)f2bf(fmaxf(acc[mi][0] + bv.x, 0.f));
        o.y = (unsigned short)f2bf(fmaxf(acc[mi][1] + bv.y, 0.f));
        o.z = (unsigned short)f2bf(fmaxf(acc[mi][2] + bv.z, 0.f));
        o.w = (unsigned short)f2bf(fmaxf(acc[mi][3] + bv.w, 0.f));
        *(ushort4*)(Hs + (wave * 16 + l16) * P3 + cb) = o;
    }
    __syncthreads();

    floatx4 acc3[5];
#pragma unroll
    for (int mi = 0; mi < 5; mi++) acc3[mi] = (floatx4){0.f, 0.f, 0.f, 0.f};
#pragma unroll
    for (int kk = 0; kk < 3; kk++) {
        short8 bb = *(const short8*)(Hs + (wave * 16 + l16) * P3 + kk * 32 + quad * 8);
#pragma unroll
        for (int mi = 0; mi < 5; mi++) {
            short8 a = *(const short8*)(W3s + (mi * 16 + l16) * P3 + kk * 32 + quad * 8);
            acc3[mi] = __builtin_amdgcn_mfma_f32_16x16x32_bf16(a, bb, acc3[mi], 0, 0, 0);
        }
    }
    int n = n0 + wave * 16 + l16;
#pragma unroll
    for (int mi = 0; mi < 5; mi++) {
        int cb = mi * 16 + quad * 4;
        float4 bv = *(const float4*)(b3 + cb);
        ushort4 o;
        o.x = (unsigned short)f2bf(acc3[mi][0] + bv.x);
        o.y = (unsigned short)f2bf(acc3[mi][1] + bv.y);
        o.z = (unsigned short)f2bf(acc3[mi][2] + bv.z);
        o.w = (unsigned short)f2bf(acc3[mi][3] + bv.w);
        *(ushort4*)(outT + (size_t)n * 80 + cb) = o;
    }
}

// ---------------------------------------------------------------------------
// attention: block = (64 t1) x b.  QK^T via MFMA; q^2 cancels; k^2 in-block.
// ---------------------------------------------------------------------------
__device__ __forceinline__ float rmax16(float v) {
#pragma unroll
    for (int o = 1; o < 16; o <<= 1) v = fmaxf(v, __shfl_xor(v, o, 64));
    return v;
}
__device__ __forceinline__ float rsum16(float v) {
#pragma unroll
    for (int o = 1; o < 16; o <<= 1) v += __shfl_xor(v, o, 64);
    return v;
}

__global__ __launch_bounds__(256) void attn_kernel(const short* __restrict__ q_encT,
                                                   const short* __restrict__ k_encT,
                                                   const float* __restrict__ prior,
                                                   const int* __restrict__ mask,
                                                   float* __restrict__ out_attn,
                                                   float* __restrict__ out_logp) {
    constexpr int T2R = 208, PITCH = 104, NPC = 12;
    __shared__ short Kt[T2R * PITCH];
    __shared__ short Qs[64 * PITCH];
    __shared__ float k2s[T2R];
    __shared__ int msk[T2R];
    const int t10 = blockIdx.x * 64, b = blockIdx.y;
    const int tid = threadIdx.x;
    const int wave = tid >> 6, lane = tid & 63;
    const int quad = lane >> 4, l16 = lane & 15;

    for (int i = tid; i < T2R * NPC; i += 256) {
        int r = i / NPC, p = i - r * NPC;
        uint4 v = {0u, 0u, 0u, 0u};
        if (r < T2 && p < 10) v = *(const uint4*)(k_encT + ((size_t)b * T2 + r) * CA + p * 8);
        *(uint4*)(Kt + r * PITCH + p * 8) = v;
    }
    for (int i = tid; i < 64 * NPC; i += 256) {
        int r = i / NPC, p = i - r * NPC;
        int t1 = t10 + r;
        uint4 v = {0u, 0u, 0u, 0u};
        if (t1 < T1 && p < 10) v = *(const uint4*)(q_encT + ((size_t)b * T1 + t1) * CA + p * 8);
        *(uint4*)(Qs + r * PITCH + p * 8) = v;
    }
    if (tid < T2R) msk[tid] = (tid < T2) ? mask[b * T2 + tid] : 0;
    __syncthreads();
    for (int r = tid; r < T2R; r += 256) {
        float s = 0.f;
        for (int p = 0; p < NPC; p++) {
            short8 v = *(const short8*)(Kt + r * PITCH + p * 8);
#pragma unroll
            for (int j = 0; j < 8; j++) { float f = bf2f(v[j]); s += f * f; }
        }
        k2s[r] = s;
    }
    __syncthreads();

    floatx4 acc[13];
#pragma unroll
    for (int n = 0; n < 13; n++) acc[n] = (floatx4){0.f, 0.f, 0.f, 0.f};
#pragma unroll
    for (int kk = 0; kk < 3; kk++) {
        short8 a = *(const short8*)(Qs + (wave * 16 + l16) * PITCH + kk * 32 + quad * 8);
#pragma unroll
        for (int n = 0; n < 13; n++) {
            short8 bb = *(const short8*)(Kt + (n * 16 + l16) * PITCH + kk * 32 + quad * 8);
            acc[n] = __builtin_amdgcn_mfma_f32_16x16x32_bf16(a, bb, acc[n], 0, 0, 0);
        }
    }

#pragma unroll
    for (int r = 0; r < 4; r++) {
        int t1 = t10 + wave * 16 + quad * 4 + r;
        bool t1ok = t1 < T1;
        float s[13];
        float mx = -INFINITY;
#pragma unroll
        for (int n = 0; n < 13; n++) {
            int t2 = n * 16 + l16;
            float sv = -INFINITY;
            if (t2 < T2) sv = -TEMP_F * (k2s[t2] - 2.f * acc[n][r]);
            s[n] = sv;
            mx = fmaxf(mx, sv);
        }
        float m = rmax16(mx);
        float sume = 0.f;
#pragma unroll
        for (int n = 0; n < 13; n++) sume += (s[n] == -INFINITY) ? 0.f : __expf(s[n] - m);
        float logZ = __logf(rsum16(sume));
        float mx2 = -INFINITY;
#pragma unroll
        for (int n = 0; n < 13; n++) {
            int t2 = n * 16 + l16;
            float pr = 1.f;
            if (t1ok && t2 < T2) pr = prior[((size_t)b * T1 + t1) * T2 + t2];
            float lp = (t2 < T2) ? (s[n] - m - logZ + __logf(pr + 1e-8f)) : -INFINITY;
            s[n] = lp;
            float ms = (t2 < T2 && msk[t2] != 0) ? lp : -INFINITY;
            mx2 = fmaxf(mx2, ms);
        }
        float m2 = rmax16(mx2);
        float sume2 = 0.f;
        float e2v[13];
#pragma unroll
        for (int n = 0; n < 13; n++) {
            int t2 = n * 16 + l16;
            float ms = (t2 < T2 && msk[t2] != 0) ? s[n] : -INFINITY;
            float e = (ms == -INFINITY) ? 0.f : __expf(ms - m2);
            e2v[n] = e;
            sume2 += e;
        }
        float Z2 = rsum16(sume2);
        if (t1ok) {
#pragma unroll
            for (int n = 0; n < 13; n++) {
                int t2 = n * 16 + l16;
                if (t2 < T2) {
                    size_t o = ((size_t)b * T1 + t1) * T2 + t2;
                    out_attn[o] = e2v[n] / Z2;
                    out_logp[o] = s[n];
                }
            }
        }
    }
}

// ---------------------------------------------------------------------------
extern "C" void kernel_launch(void* const* d_in, const int* in_sizes, int n_in,
                              void* d_out, int out_size, void* d_ws, size_t ws_size,
                              hipStream_t stream) {
    const float* queries = (const float*)d_in[0];
    const float* keys    = (const float*)d_in[1];
    const int*   mask    = (const int*)d_in[2];
    const float* prior   = (const float*)d_in[3];
    const float* g       = (const float*)d_in[4];
    const float* wk1 = (const float*)d_in[5];
    const float* bk1 = (const float*)d_in[6];
    const float* wk2 = (const float*)d_in[7];
    const float* bk2 = (const float*)d_in[8];
    const float* wq1 = (const float*)d_in[9];
    const float* bq1 = (const float*)d_in[10];
    const float* wq2 = (const float*)d_in[11];
    const float* bq2 = (const float*)d_in[12];
    const float* wq3 = (const float*)d_in[13];
    const float* bq3 = (const float*)d_in[14];
    const float* w_kspk = (const float*)d_in[15];
    const float* b_kspk = (const float*)d_in[16];
    const float* w_qspk = (const float*)d_in[17];
    const float* b_qspk = (const float*)d_in[18];

    // ---- workspace layout (shorts unless noted) ----
    float* kspk = (float*)d_ws;                      // 8192 fp32
    float* qspk = kspk + 8192;                       // 1280 fp32
    short* wsS  = (short*)d_ws;
    short* xkT   = wsS + 20480;                      // 16x200x512
    short* xqT   = wsS + 1658880;                    // 16x1000x80
    short* wk1b  = wsS + 2938880;                    // 3x1024x512
    short* wk2b  = wsS + 4511744;                    // 80x1024
    short* wq1b  = wsS + 4593664;                    // 3x160x80
    short* wq2b  = wsS + 4632064;                    // 80x160
    short* wq3b  = wsS + 4644864;                    // 80x80
    short* k_encT = wsS + 4651264;                   // 3200x80
    short* q_encT = wsS + 4907264;                   // 16000x80 -> ends 6187264
    float* part  = (float*)d_ws + 3093632;           // 8x3200x80 fp32 (ends 20.6 MB)
    // hidden layers in d_out (consumed before attn overwrites):
    short* doS  = (short*)d_out;
    short* kh1T = doS;                               // 3200x1024 (6.55 MB)
    short* qh1T = doS + 3276800;                     // 16000x160 (5.12 MB)

    // 1. prep
    spk_kernel<<<dim3((NB * (CT + CS) * 64 + 255) / 256), dim3(256), 0, stream>>>(
        g, w_kspk, b_kspk, w_qspk, b_qspk, kspk, qspk);
    convertW_kernel<C2T, CT, 3><<<dim3((3 * C2T * CT + 255) / 256), dim3(256), 0, stream>>>(wk1, wk1b);
    convertW_kernel<CA, C2T, 1><<<dim3((CA * C2T + 255) / 256), dim3(256), 0, stream>>>(wk2, wk2b);
    convertW_kernel<C2S, CS, 3><<<dim3((3 * C2S * CS + 255) / 256), dim3(256), 0, stream>>>(wq1, wq1b);
    convertW_kernel<CS, C2S, 1><<<dim3((CS * C2S + 255) / 256), dim3(256), 0, stream>>>(wq2, wq2b);
    convertW_kernel<CA, CS, 1><<<dim3((CA * CS + 255) / 256), dim3(256), 0, stream>>>(wq3, wq3b);
    addspkT_kernel<CT, T2><<<dim3(4, 16, NB), dim3(256), 0, stream>>>(keys, kspk, xkT);
    addspkT_kernel<CS, T1><<<dim3(16, 3, NB), dim3(256), 0, stream>>>(queries, qspk, xqT);

    // 2. key path: conv3 (MFMA, 512 blocks), then split-K 1x1 GEMM (400 blocks) + combine
    conv_mfma<CT, C2T, T2, 3, true, 64, 128, 32, 64, 64>
        <<<dim3(2, 16, NB), dim3(256), 0, stream>>>(xkT, wk1b, bk1, kh1T);
    gemm_splitk<C2T, CA, NB * T2, 64, 8, 64>
        <<<dim3(50, 8), dim3(256), 0, stream>>>(kh1T, wk2b, part);
    combine_kernel<CA, NB * T2, 8>
        <<<dim3((NB * T2 * (CA / 4) + 255) / 256), dim3(256), 0, stream>>>(part, bk2, k_encT);
    // 3. query path: conv3 (384 blocks) then fused conv2+conv3 (250 blocks)
    conv_mfma<CS, C2S, T1, 3, true, 64, 128, 32, 64, 96>
        <<<dim3(8, 3, NB), dim3(256), 0, stream>>>(xqT, wq1b, bq1, qh1T);
    qconv23_kernel<<<dim3(NB * T1 / 64), dim3(256), 0, stream>>>(qh1T, wq2b, bq2, wq3b, bq3, q_encT);
    // 4. attention
    float* out_attn = (float*)d_out;
    float* out_logp = out_attn + (size_t)NB * T1 * T2;
    attn_kernel<<<dim3(16, NB), dim3(256), 0, stream>>>(q_encT, k_encT, prior, mask,
                                                        out_attn, out_logp);
}

// Round 6
// 220.115 us; speedup vs baseline: 6.2849x; 1.0962x over previous
//
#include <hip/hip_runtime.h>
#include <hip/hip_bf16.h>
#include <math.h>

#define NB 16      // batch
#define CS 80      // spec channels
#define T1 1000    // mel frames
#define CT 512     // text channels
#define T2 200     // phonemes
#define CA 80      // attn channels
#define GD 256     // speaker dim
#define C2T 1024   // 2*Ct
#define C2S 160    // 2*Cs
#define TEMP_F 0.0005f

typedef __attribute__((ext_vector_type(8))) short short8;
typedef __attribute__((ext_vector_type(4))) float floatx4;

// fp32 -> bf16 bits, round-to-nearest-even
__device__ __forceinline__ short f2bf(float x) {
    unsigned u = __builtin_bit_cast(unsigned, x);
    unsigned r = (u + 0x7fffu + ((u >> 16) & 1u)) >> 16;
    return (short)r;
}
__device__ __forceinline__ float bf2f(short s) {
    unsigned u = ((unsigned)(unsigned short)s) << 16;
    return __builtin_bit_cast(float, u);
}

// ---------------------------------------------------------------------------
// speaker projections, one wave per output channel (coalesced weight rows)
// ---------------------------------------------------------------------------
__global__ __launch_bounds__(256) void spk_kernel(const float* __restrict__ g,
                           const float* __restrict__ w_kspk, const float* __restrict__ b_kspk,
                           const float* __restrict__ w_qspk, const float* __restrict__ b_qspk,
                           float* __restrict__ kspk, float* __restrict__ qspk) {
    int w = (blockIdx.x * 256 + threadIdx.x) >> 6;
    int lane = threadIdx.x & 63;
    const int NK = NB * CT;
    const float* wrow;
    float bias;
    float* dst;
    int b;
    if (w < NK) {
        b = w >> 9;
        int c = w & 511;
        wrow = w_kspk + (size_t)c * GD; bias = b_kspk[c]; dst = kspk + w;
    } else if (w < NK + NB * CS) {
        int i2 = w - NK;
        b = i2 / CS;
        int c = i2 - b * CS;
        wrow = w_qspk + (size_t)c * GD; bias = b_qspk[c]; dst = qspk + i2;
    } else return;
    float s = 0.f;
#pragma unroll
    for (int j = lane; j < GD; j += 64) s += g[b * GD + j] * wrow[j];
#pragma unroll
    for (int o = 1; o < 64; o <<= 1) s += __shfl_xor(s, o, 64);
    if (lane == 0) *dst = s + bias;
}

// ---------------------------------------------------------------------------
// fused speaker-add + transpose: in fp32 [b][C][T] + spk[b][C] -> out bf16 [b][T][C]
// ---------------------------------------------------------------------------
template <int C, int T>
__global__ __launch_bounds__(256) void addspkT_kernel(const float* __restrict__ in,
                                                      const float* __restrict__ spk,
                                                      short* __restrict__ outT) {
    __shared__ float S[32][65];
    const int t0 = blockIdx.x * 64, c0 = blockIdx.y * 32, b = blockIdx.z;
    const int tid = threadIdx.x;
    for (int i = tid; i < 32 * 64; i += 256) {
        int cl = i >> 6, tl = i & 63;
        int gc = c0 + cl, gt = t0 + tl;
        float v = 0.f;
        if (gc < C && gt < T) v = in[((size_t)b * C + gc) * T + gt] + spk[b * C + gc];
        S[cl][tl] = v;
    }
    __syncthreads();
    for (int i = tid; i < 64 * 32; i += 256) {
        int tl = i >> 5, cl = i & 31;
        int gt = t0 + tl, gc = c0 + cl;
        if (gc < C && gt < T) outT[((size_t)b * T + gt) * C + gc] = f2bf(S[cl][tl]);
    }
}

// ---------------------------------------------------------------------------
// weight pack into MFMA A-fragment-major layout:
//   wp[((co16*KW + k)*NC32T + ci32)*512 + lane*8 + j]
//   co = co16*16 + (lane&15), ci = ci32*32 + (lane>>4)*8 + j
// from w fp32 [COUT][CIN][KW].  One thread per (frag, lane) -> 16B store.
// ---------------------------------------------------------------------------
template <int COUT, int CIN, int KW, int COP, int CINP>
__global__ __launch_bounds__(256) void wpack_kernel(const float* __restrict__ w,
                                                    short* __restrict__ wp) {
    constexpr int NC32 = CINP / 32;
    constexpr int NFRAG = (COP / 16) * KW * NC32;
    int gid = blockIdx.x * 256 + threadIdx.x;
    int frag = gid >> 6, lane = gid & 63;
    if (frag >= NFRAG) return;
    int co16 = frag / (KW * NC32), rem = frag - co16 * (KW * NC32);
    int k = rem / NC32, ci32 = rem - k * NC32;
    int co = co16 * 16 + (lane & 15);
    int ci = ci32 * 32 + (lane >> 4) * 8;
    short8 v;
#pragma unroll
    for (int j = 0; j < 8; j++) {
        float f = 0.f;
        if (co < COUT && ci + j < CIN) f = w[((size_t)co * CIN + ci + j) * KW + k];
        v[j] = f2bf(f);
    }
    *(short8*)(wp + (size_t)frag * 512 + lane * 8) = v;
}

// ---------------------------------------------------------------------------
// fused fp32->bf16 convert for the three 1x1 weights (row-major kept)
// ---------------------------------------------------------------------------
__global__ void convert3_kernel(const float* __restrict__ wk2, const float* __restrict__ wq2,
                                const float* __restrict__ wq3, short* __restrict__ wk2b,
                                short* __restrict__ wq2b, short* __restrict__ wq3b) {
    int i = blockIdx.x * 256 + threadIdx.x;
    const int N1 = CA * C2T, N2 = CA * C2S, N3 = CA * CS;
    if (i < N1) wk2b[i] = f2bf(wk2[i]);
    else if (i < N1 + N2) wq2b[i - N1] = f2bf(wq2[i - N1]);
    else if (i < N1 + N2 + N3) wq3b[i - N1 - N2] = f2bf(wq3[i - N1 - N2]);
}

// ---------------------------------------------------------------------------
// k=3 conv as GEMM, W read directly from global in A-fragment layout (L1/L2),
// X staged in LDS (double-buffered, register prefetch).  Block: 64co x 128t,
// 4 t-stacked waves (each 64co x 32t; MT=4, NT=2).  16x16x32 bf16 MFMA:
//   A lane m=l16(co), k=quad*8+j;  B lane n=l16(t), k=quad*8+j
//   D lane reg r: row(co)=quad*4+r, col(t)=l16   (validated rounds 3-5)
// ---------------------------------------------------------------------------
template <int CIN, int COUT, int T, int KW, bool RELU, int CICH, int NC32T>
__global__ __launch_bounds__(256, 2) void conv_wg(const short* __restrict__ xT,
                                                  const short* __restrict__ wp,
                                                  const float* __restrict__ bias,
                                                  short* __restrict__ outT) {
    constexpr int TT = 128, COT = 64;
    constexpr int PAD = KW / 2;
    constexpr int XROWS = TT + KW - 1;
    constexpr int PITCH = CICH + 8;          // row stride: 2-way-only bank pattern
    constexpr int NPC = CICH / 8;
    constexpr int NC32 = CICH / 32;
    constexpr int CINP = NC32T * 32;
    constexpr int NCHK = CINP / CICH;
    constexpr int NPIECE = XROWS * NPC;
    constexpr int NLD = (NPIECE + 255) / 256;
    constexpr int NBUF = (NCHK > 1) ? 2 : 1;
    __shared__ short Xs[NBUF * XROWS * PITCH];

    const int t0 = blockIdx.x * TT, co0 = blockIdx.y * COT, b = blockIdx.z;
    const int tid = threadIdx.x, wave = tid >> 6, lane = tid & 63;
    const int quad = lane >> 4, l16 = lane & 15;
    const int wt = wave * 32;
    const int co16_0 = co0 >> 4;
    const short* xb = xT + (size_t)b * T * CIN;

    floatx4 acc[4][2];
#pragma unroll
    for (int mi = 0; mi < 4; mi++)
#pragma unroll
        for (int ni = 0; ni < 2; ni++) acc[mi][ni] = (floatx4){0.f, 0.f, 0.f, 0.f};

    // stage chunk 0 into buffer 0
    for (int i = tid; i < NPIECE; i += 256) {
        int r = i / NPC, p = i - r * NPC;
        int t = t0 + r - PAD, ci = p * 8;
        uint4 v = {0u, 0u, 0u, 0u};
        if ((unsigned)t < (unsigned)T && ci + 8 <= CIN)
            v = *(const uint4*)(xb + (size_t)t * CIN + ci);
        *(uint4*)(Xs + r * PITCH + p * 8) = v;
    }
    __syncthreads();

    for (int kc = 0; kc < NCHK; kc++) {
        // register-prefetch next chunk's X (overlaps with MFMA below)
        uint4 tmp[NLD];
        if (kc + 1 < NCHK) {
            int ci0n = (kc + 1) * CICH;
#pragma unroll
            for (int ld = 0; ld < NLD; ld++) {
                int i = tid + ld * 256;
                tmp[ld] = (uint4){0u, 0u, 0u, 0u};
                if (i < NPIECE) {
                    int r = i / NPC, p = i - r * NPC;
                    int t = t0 + r - PAD, ci = ci0n + p * 8;
                    if ((unsigned)t < (unsigned)T && ci + 8 <= CIN)
                        tmp[ld] = *(const uint4*)(xb + (size_t)t * CIN + ci);
                }
            }
        }
        const short* Xb = Xs + (NBUF > 1 ? (kc & 1) : 0) * XROWS * PITCH;
#pragma unroll
        for (int k = 0; k < KW; k++) {
#pragma unroll
            for (int kk = 0; kk < NC32; kk++) {
                int ci32 = kc * NC32 + kk;
                short8 a[4];
#pragma unroll
                for (int mi = 0; mi < 4; mi++)
                    a[mi] = *(const short8*)(wp +
                        ((size_t)((co16_0 + mi) * KW + k) * NC32T + ci32) * 512 + lane * 8);
#pragma unroll
                for (int ni = 0; ni < 2; ni++) {
                    short8 bb = *(const short8*)(Xb + (wt + ni * 16 + l16 + k) * PITCH +
                                                 kk * 32 + quad * 8);
#pragma unroll
                    for (int mi = 0; mi < 4; mi++)
                        acc[mi][ni] = __builtin_amdgcn_mfma_f32_16x16x32_bf16(a[mi], bb,
                                                                              acc[mi][ni], 0, 0, 0);
                }
            }
        }
        if (kc + 1 < NCHK) {
            short* Xn = Xs + ((kc + 1) & 1) * XROWS * PITCH;
#pragma unroll
            for (int ld = 0; ld < NLD; ld++) {
                int i = tid + ld * 256;
                if (i < NPIECE) {
                    int r = i / NPC, p = i - r * NPC;
                    *(uint4*)(Xn + r * PITCH + p * 8) = tmp[ld];
                }
            }
            __syncthreads();
        }
    }
    // epilogue: D row(co)=quad*4+r, col(t)=l16; pack 4 co into one 8B store
#pragma unroll
    for (int mi = 0; mi < 4; mi++) {
        int cb = co0 + mi * 16 + quad * 4;
        if (cb < COUT) {
            float4 bv = *(const float4*)(bias + cb);
#pragma unroll
            for (int ni = 0; ni < 2; ni++) {
                int t = t0 + wt + ni * 16 + l16;
                if (t < T) {
                    float v0 = acc[mi][ni][0] + bv.x, v1 = acc[mi][ni][1] + bv.y;
                    float v2 = acc[mi][ni][2] + bv.z, v3 = acc[mi][ni][3] + bv.w;
                    if (RELU) {
                        v0 = fmaxf(v0, 0.f); v1 = fmaxf(v1, 0.f);
                        v2 = fmaxf(v2, 0.f); v3 = fmaxf(v3, 0.f);
                    }
                    ushort4 o;
                    o.x = (unsigned short)f2bf(v0); o.y = (unsigned short)f2bf(v1);
                    o.z = (unsigned short)f2bf(v2); o.w = (unsigned short)f2bf(v3);
                    *(ushort4*)(outT + ((size_t)b * T + t) * COUT + cb) = o;
                }
            }
        }
    }
}

// ---------------------------------------------------------------------------
// batch-merged 1x1 split-K GEMM: xT [NTOT][K] bf16, w [COUT][K] bf16 ->
// part[s][NTOT][COUT] fp32.
// ---------------------------------------------------------------------------
template <int K, int COUT, int NTOT, int NTILE, int SPLITK, int CICH>
__global__ __launch_bounds__(256) void gemm_splitk(const short* __restrict__ xT,
                                                   const short* __restrict__ w,
                                                   float* __restrict__ part) {
    constexpr int PITCH = CICH + 8, NPC = CICH / 8;
    constexpr int KSP = K / SPLITK;
    constexpr int NKC = KSP / CICH;
    constexpr int MT = COUT / 16;
    __shared__ short Xs[NTILE * PITCH];
    __shared__ short Ws[COUT * PITCH];
    const int n0 = blockIdx.x * NTILE;
    const int s = blockIdx.y;
    const int tid = threadIdx.x, wave = tid >> 6, lane = tid & 63;
    const int quad = lane >> 4, l16 = lane & 15;
    floatx4 acc[MT];
#pragma unroll
    for (int mi = 0; mi < MT; mi++) acc[mi] = (floatx4){0.f, 0.f, 0.f, 0.f};

    for (int kc = 0; kc < NKC; kc++) {
        const int ci0 = s * KSP + kc * CICH;
        if (kc) __syncthreads();
        for (int i = tid; i < NTILE * NPC; i += 256) {
            int r = i / NPC, p = i - r * NPC;
            *(uint4*)(Xs + r * PITCH + p * 8) =
                *(const uint4*)(xT + (size_t)(n0 + r) * K + ci0 + p * 8);
        }
        for (int i = tid; i < COUT * NPC; i += 256) {
            int r = i / NPC, p = i - r * NPC;
            *(uint4*)(Ws + r * PITCH + p * 8) =
                *(const uint4*)(w + (size_t)r * K + ci0 + p * 8);
        }
        __syncthreads();
#pragma unroll
        for (int kk = 0; kk < CICH / 32; kk++) {
            short8 bb = *(const short8*)(Xs + (wave * 16 + l16) * PITCH + kk * 32 + quad * 8);
#pragma unroll
            for (int mi = 0; mi < MT; mi++) {
                short8 a = *(const short8*)(Ws + (mi * 16 + l16) * PITCH + kk * 32 + quad * 8);
                acc[mi] = __builtin_amdgcn_mfma_f32_16x16x32_bf16(a, bb, acc[mi], 0, 0, 0);
            }
        }
    }
    int n = n0 + wave * 16 + l16;
#pragma unroll
    for (int mi = 0; mi < MT; mi++) {
        int cb = mi * 16 + quad * 4;
        float4 o = {acc[mi][0], acc[mi][1], acc[mi][2], acc[mi][3]};
        *(float4*)(part + ((size_t)s * NTOT + n) * COUT + cb) = o;
    }
}

// combine split-K partials + bias -> bf16 [NTOT][COUT]
template <int COUT, int NTOT, int SPLITK>
__global__ void combine_kernel(const float* __restrict__ part, const float* __restrict__ bias,
                               short* __restrict__ outT) {
    int i = blockIdx.x * 256 + threadIdx.x;
    if (i >= NTOT * (COUT / 4)) return;
    int n = i / (COUT / 4), c4 = i - n * (COUT / 4);
    int co = c4 * 4;
    float4 s = {0.f, 0.f, 0.f, 0.f};
#pragma unroll
    for (int k = 0; k < SPLITK; k++) {
        float4 v = *(const float4*)(part + ((size_t)k * NTOT + n) * COUT + co);
        s.x += v.x; s.y += v.y; s.z += v.z; s.w += v.w;
    }
    float4 b = *(const float4*)(bias + co);
    ushort4 o;
    o.x = (unsigned short)f2bf(s.x + b.x); o.y = (unsigned short)f2bf(s.y + b.y);
    o.z = (unsigned short)f2bf(s.z + b.z); o.w = (unsigned short)f2bf(s.w + b.w);
    *(ushort4*)(outT + (size_t)n * COUT + co) = o;
}

// ---------------------------------------------------------------------------
// fused query conv2(160->80,relu) + conv3(80->80): h1 [16000][160] bf16 ->
// q_encT [16000][80] bf16.
// ---------------------------------------------------------------------------
__global__ __launch_bounds__(256) void qconv23_kernel(const short* __restrict__ h1,
                                                      const short* __restrict__ w2,
                                                      const float* __restrict__ b2,
                                                      const short* __restrict__ w3,
                                                      const float* __restrict__ b3,
                                                      short* __restrict__ outT) {
    constexpr int K1 = 160, P1 = 168, NPC1 = 20;
    constexpr int P3 = 104, NPC3 = 12;
    __shared__ short Xs[64 * P1];
    __shared__ short W2s[80 * P1];
    __shared__ short W3s[80 * P3];
    __shared__ short Hs[64 * P3];
    const int n0 = blockIdx.x * 64;
    const int tid = threadIdx.x, wave = tid >> 6, lane = tid & 63;
    const int quad = lane >> 4, l16 = lane & 15;

    for (int i = tid; i < 64 * NPC1; i += 256) {
        int r = i / NPC1, p = i - r * NPC1;
        *(uint4*)(Xs + r * P1 + p * 8) = *(const uint4*)(h1 + (size_t)(n0 + r) * K1 + p * 8);
    }
    for (int i = tid; i < 80 * NPC1; i += 256) {
        int r = i / NPC1, p = i - r * NPC1;
        *(uint4*)(W2s + r * P1 + p * 8) = *(const uint4*)(w2 + (size_t)r * K1 + p * 8);
    }
    for (int i = tid; i < 80 * NPC3; i += 256) {
        int r = i / NPC3, p = i - r * NPC3;
        uint4 v = {0u, 0u, 0u, 0u};
        if (p < 10) v = *(const uint4*)(w3 + (size_t)r * 80 + p * 8);
        *(uint4*)(W3s + r * P3 + p * 8) = v;
    }
    if (tid < 128) *(uint4*)(Hs + (tid >> 1) * P3 + 80 + (tid & 1) * 8) = (uint4){0u, 0u, 0u, 0u};
    __syncthreads();

    floatx4 acc[5];
#pragma unroll
    for (int mi = 0; mi < 5; mi++) acc[mi] = (floatx4){0.f, 0.f, 0.f, 0.f};
#pragma unroll
    for (int kk = 0; kk < 5; kk++) {
        short8 bb = *(const short8*)(Xs + (wave * 16 + l16) * P1 + kk * 32 + quad * 8);
#pragma unroll
        for (int mi = 0; mi < 5; mi++) {
            short8 a = *(const short8*)(W2s + (mi * 16 + l16) * P1 + kk * 32 + quad * 8);
            acc[mi] = __builtin_amdgcn_mfma_f32_16x16x32_bf16(a, bb, acc[mi], 0, 0, 0);
        }
    }
#pragma unroll
    for (int mi = 0; mi < 5; mi++) {
        int cb = mi * 16 + quad * 4;
        float4 bv = *(const float4*)(b2 + cb);
        ushort4 o;
        o.x = (unsigned short)f2bf(fmaxf(acc[mi][0] + bv.x, 0.f));
        o.y = (unsigned short)f2bf(fmaxf(acc[mi][1] + bv.y, 0.f));
        o.z = (unsigned short)f2bf(fmaxf(acc[mi][2] + bv.z, 0.f));
        o.w = (unsigned short)f2bf(fmaxf(acc[mi][3] + bv.w, 0.f));
        *(ushort4*)(Hs + (wave * 16 + l16) * P3 + cb) = o;
    }
    __syncthreads();

    floatx4 acc3[5];
#pragma unroll
    for (int mi = 0; mi < 5; mi++) acc3[mi] = (floatx4){0.f, 0.f, 0.f, 0.f};
#pragma unroll
    for (int kk = 0; kk < 3; kk++) {
        short8 bb = *(const short8*)(Hs + (wave * 16 + l16) * P3 + kk * 32 + quad * 8);
#pragma unroll
        for (int mi = 0; mi < 5; mi++) {
            short8 a = *(const short8*)(W3s + (mi * 16 + l16) * P3 + kk * 32 + quad * 8);
            acc3[mi] = __builtin_amdgcn_mfma_f32_16x16x32_bf16(a, bb, acc3[mi], 0, 0, 0);
        }
    }
    int n = n0 + wave * 16 + l16;
#pragma unroll
    for (int mi = 0; mi < 5; mi++) {
        int cb = mi * 16 + quad * 4;
        float4 bv = *(const float4*)(b3 + cb);
        ushort4 o;
        o.x = (unsigned short)f2bf(acc3[mi][0] + bv.x);
        o.y = (unsigned short)f2bf(acc3[mi][1] + bv.y);
        o.z = (unsigned short)f2bf(acc3[mi][2] + bv.z);
        o.w = (unsigned short)f2bf(acc3[mi][3] + bv.w);
        *(ushort4*)(outT + (size_t)n * 80 + cb) = o;
    }
}

// ---------------------------------------------------------------------------
// attention: block = (64 t1) x b.  QK^T via MFMA; q^2 cancels; k^2 in-block.
// ---------------------------------------------------------------------------
__device__ __forceinline__ float rmax16(float v) {
#pragma unroll
    for (int o = 1; o < 16; o <<= 1) v = fmaxf(v, __shfl_xor(v, o, 64));
    return v;
}
__device__ __forceinline__ float rsum16(float v) {
#pragma unroll
    for (int o = 1; o < 16; o <<= 1) v += __shfl_xor(v, o, 64);
    return v;
}

__global__ __launch_bounds__(256) void attn_kernel(const short* __restrict__ q_encT,
                                                   const short* __restrict__ k_encT,
                                                   const float* __restrict__ prior,
                                                   const int* __restrict__ mask,
                                                   float* __restrict__ out_attn,
                                                   float* __restrict__ out_logp) {
    constexpr int T2R = 208, PITCH = 104, NPC = 12;
    __shared__ short Kt[T2R * PITCH];
    __shared__ short Qs[64 * PITCH];
    __shared__ float k2s[T2R];
    __shared__ int msk[T2R];
    const int t10 = blockIdx.x * 64, b = blockIdx.y;
    const int tid = threadIdx.x;
    const int wave = tid >> 6, lane = tid & 63;
    const int quad = lane >> 4, l16 = lane & 15;

    for (int i = tid; i < T2R * NPC; i += 256) {
        int r = i / NPC, p = i - r * NPC;
        uint4 v = {0u, 0u, 0u, 0u};
        if (r < T2 && p < 10) v = *(const uint4*)(k_encT + ((size_t)b * T2 + r) * CA + p * 8);
        *(uint4*)(Kt + r * PITCH + p * 8) = v;
    }
    for (int i = tid; i < 64 * NPC; i += 256) {
        int r = i / NPC, p = i - r * NPC;
        int t1 = t10 + r;
        uint4 v = {0u, 0u, 0u, 0u};
        if (t1 < T1 && p < 10) v = *(const uint4*)(q_encT + ((size_t)b * T1 + t1) * CA + p * 8);
        *(uint4*)(Qs + r * PITCH + p * 8) = v;
    }
    if (tid < T2R) msk[tid] = (tid < T2) ? mask[b * T2 + tid] : 0;
    __syncthreads();
    for (int r = tid; r < T2R; r += 256) {
        float s = 0.f;
        for (int p = 0; p < NPC; p++) {
            short8 v = *(const short8*)(Kt + r * PITCH + p * 8);
#pragma unroll
            for (int j = 0; j < 8; j++) { float f = bf2f(v[j]); s += f * f; }
        }
        k2s[r] = s;
    }
    __syncthreads();

    floatx4 acc[13];
#pragma unroll
    for (int n = 0; n < 13; n++) acc[n] = (floatx4){0.f, 0.f, 0.f, 0.f};
#pragma unroll
    for (int kk = 0; kk < 3; kk++) {
        short8 a = *(const short8*)(Qs + (wave * 16 + l16) * PITCH + kk * 32 + quad * 8);
#pragma unroll
        for (int n = 0; n < 13; n++) {
            short8 bb = *(const short8*)(Kt + (n * 16 + l16) * PITCH + kk * 32 + quad * 8);
            acc[n] = __builtin_amdgcn_mfma_f32_16x16x32_bf16(a, bb, acc[n], 0, 0, 0);
        }
    }

#pragma unroll
    for (int r = 0; r < 4; r++) {
        int t1 = t10 + wave * 16 + quad * 4 + r;
        bool t1ok = t1 < T1;
        float s[13];
        float mx = -INFINITY;
#pragma unroll
        for (int n = 0; n < 13; n++) {
            int t2 = n * 16 + l16;
            float sv = -INFINITY;
            if (t2 < T2) sv = -TEMP_F * (k2s[t2] - 2.f * acc[n][r]);
            s[n] = sv;
            mx = fmaxf(mx, sv);
        }
        float m = rmax16(mx);
        float sume = 0.f;
#pragma unroll
        for (int n = 0; n < 13; n++) sume += (s[n] == -INFINITY) ? 0.f : __expf(s[n] - m);
        float logZ = __logf(rsum16(sume));
        float mx2 = -INFINITY;
#pragma unroll
        for (int n = 0; n < 13; n++) {
            int t2 = n * 16 + l16;
            float pr = 1.f;
            if (t1ok && t2 < T2) pr = prior[((size_t)b * T1 + t1) * T2 + t2];
            float lp = (t2 < T2) ? (s[n] - m - logZ + __logf(pr + 1e-8f)) : -INFINITY;
            s[n] = lp;
            float ms = (t2 < T2 && msk[t2] != 0) ? lp : -INFINITY;
            mx2 = fmaxf(mx2, ms);
        }
        float m2 = rmax16(mx2);
        float sume2 = 0.f;
        float e2v[13];
#pragma unroll
        for (int n = 0; n < 13; n++) {
            int t2 = n * 16 + l16;
            float ms = (t2 < T2 && msk[t2] != 0) ? s[n] : -INFINITY;
            float e = (ms == -INFINITY) ? 0.f : __expf(ms - m2);
            e2v[n] = e;
            sume2 += e;
        }
        float Z2 = rsum16(sume2);
        if (t1ok) {
#pragma unroll
            for (int n = 0; n < 13; n++) {
                int t2 = n * 16 + l16;
                if (t2 < T2) {
                    size_t o = ((size_t)b * T1 + t1) * T2 + t2;
                    out_attn[o] = e2v[n] / Z2;
                    out_logp[o] = s[n];
                }
            }
        }
    }
}

// ---------------------------------------------------------------------------
extern "C" void kernel_launch(void* const* d_in, const int* in_sizes, int n_in,
                              void* d_out, int out_size, void* d_ws, size_t ws_size,
                              hipStream_t stream) {
    const float* queries = (const float*)d_in[0];
    const float* keys    = (const float*)d_in[1];
    const int*   mask    = (const int*)d_in[2];
    const float* prior   = (const float*)d_in[3];
    const float* g       = (const float*)d_in[4];
    const float* wk1 = (const float*)d_in[5];
    const float* bk1 = (const float*)d_in[6];
    const float* wk2 = (const float*)d_in[7];
    const float* bk2 = (const float*)d_in[8];
    const float* wq1 = (const float*)d_in[9];
    const float* bq1 = (const float*)d_in[10];
    const float* wq2 = (const float*)d_in[11];
    const float* bq2 = (const float*)d_in[12];
    const float* wq3 = (const float*)d_in[13];
    const float* bq3 = (const float*)d_in[14];
    const float* w_kspk = (const float*)d_in[15];
    const float* b_kspk = (const float*)d_in[16];
    const float* w_qspk = (const float*)d_in[17];
    const float* b_qspk = (const float*)d_in[18];

    // ---- workspace layout (shorts unless noted) ----
    float* kspk = (float*)d_ws;                      // 8192 fp32
    float* qspk = kspk + 8192;                       // 1280 fp32
    short* wsS  = (short*)d_ws;
    short* xkT   = wsS + 20480;                      // 16x200x512     -> 1,658,880
    short* xqT   = wsS + 1658880;                    // 16x1000x80     -> 2,938,880
    short* wk1p  = wsS + 2938880;                    // 64x3x16x512    -> 4,511,744
    short* wk2b  = wsS + 4511744;                    // 80x1024        -> 4,593,664
    short* wq1p  = wsS + 4593664;                    // 12x3x3x512     -> 4,648,960
    short* wq2b  = wsS + 4648960;                    // 80x160         -> 4,661,760
    short* wq3b  = wsS + 4661760;                    // 80x80          -> 4,668,160
    short* k_encT = wsS + 4668160;                   // 3200x80        -> 4,924,160
    short* q_encT = wsS + 4924160;                   // 16000x80       -> 6,204,160
    float* part  = (float*)d_ws + 3102080;           // 8x3200x80 fp32 (ends 20.6 MB)
    // hidden layers in d_out (consumed before attn overwrites):
    short* doS  = (short*)d_out;
    short* kh1T = doS;                               // 3200x1024 (6.55 MB)
    short* qh1T = doS + 3276800;                     // 16000x160 (5.12 MB)

    // 1. prep
    spk_kernel<<<dim3((NB * (CT + CS) * 64 + 255) / 256), dim3(256), 0, stream>>>(
        g, w_kspk, b_kspk, w_qspk, b_qspk, kspk, qspk);
    wpack_kernel<C2T, CT, 3, C2T, CT>
        <<<dim3((64 * 3 * 16 * 64 + 255) / 256), dim3(256), 0, stream>>>(wk1, wk1p);
    wpack_kernel<C2S, CS, 3, 192, 96>
        <<<dim3((12 * 3 * 3 * 64 + 255) / 256), dim3(256), 0, stream>>>(wq1, wq1p);
    convert3_kernel<<<dim3((CA * (C2T + C2S + CS) + 255) / 256), dim3(256), 0, stream>>>(
        wk2, wq2, wq3, wk2b, wq2b, wq3b);
    addspkT_kernel<CT, T2><<<dim3(4, 16, NB), dim3(256), 0, stream>>>(keys, kspk, xkT);
    addspkT_kernel<CS, T1><<<dim3(16, 3, NB), dim3(256), 0, stream>>>(queries, qspk, xqT);

    // 2. key path: conv3 (W-from-global MFMA, 512 blocks), split-K 1x1 + combine
    conv_wg<CT, C2T, T2, 3, true, 64, 16>
        <<<dim3(2, 16, NB), dim3(256), 0, stream>>>(xkT, wk1p, bk1, kh1T);
    gemm_splitk<C2T, CA, NB * T2, 64, 8, 64>
        <<<dim3(50, 8), dim3(256), 0, stream>>>(kh1T, wk2b, part);
    combine_kernel<CA, NB * T2, 8>
        <<<dim3((NB * T2 * (CA / 4) + 255) / 256), dim3(256), 0, stream>>>(part, bk2, k_encT);
    // 3. query path: conv3 (384 blocks) then fused conv2+conv3 (250 blocks)
    conv_wg<CS, C2S, T1, 3, true, 96, 3>
        <<<dim3(8, 3, NB), dim3(256), 0, stream>>>(xqT, wq1p, bq1, qh1T);
    qconv23_kernel<<<dim3(NB * T1 / 64), dim3(256), 0, stream>>>(qh1T, wq2b, bq2, wq3b, bq3, q_encT);
    // 4. attention
    float* out_attn = (float*)d_out;
    float* out_logp = out_attn + (size_t)NB * T1 * T2;
    attn_kernel<<<dim3(16, NB), dim3(256), 0, stream>>>(q_encT, k_encT, prior, mask,
                                                        out_attn, out_logp);
}

// Round 7
// 211.163 us; speedup vs baseline: 6.5513x; 1.0424x over previous
//
#include <hip/hip_runtime.h>
#include <hip/hip_bf16.h>
#include <math.h>

#define NB 16      // batch
#define CS 80      // spec channels
#define T1 1000    // mel frames
#define CT 512     // text channels
#define T2 200     // phonemes
#define CA 80      // attn channels
#define GD 256     // speaker dim
#define C2T 1024   // 2*Ct
#define C2S 160    // 2*Cs
#define TEMP_F 0.0005f

typedef __attribute__((ext_vector_type(8))) short short8;
typedef __attribute__((ext_vector_type(4))) float floatx4;

// fp32 -> bf16 bits, round-to-nearest-even
__device__ __forceinline__ short f2bf(float x) {
    unsigned u = __builtin_bit_cast(unsigned, x);
    unsigned r = (u + 0x7fffu + ((u >> 16) & 1u)) >> 16;
    return (short)r;
}
__device__ __forceinline__ float bf2f(short s) {
    unsigned u = ((unsigned)(unsigned short)s) << 16;
    return __builtin_bit_cast(float, u);
}

// ---------------------------------------------------------------------------
// weight pack into MFMA A-fragment-major layout:
//   wp[((co16*KW + k)*NC32 + ci32)*512 + lane*8 + j]
//   co = co16*16 + (lane&15), ci = ci32*32 + (lane>>4)*8 + j
// ---------------------------------------------------------------------------
template <int COUT, int CIN, int KW, int COP, int CINP>
__device__ __forceinline__ void wpack_body(const float* __restrict__ w,
                                           short* __restrict__ wp, int bid) {
    constexpr int NC32 = CINP / 32;
    constexpr int NFRAG = (COP / 16) * KW * NC32;
    int gid = bid * 256 + threadIdx.x;
    int frag = gid >> 6, lane = gid & 63;
    if (frag >= NFRAG) return;
    int co16 = frag / (KW * NC32), rem = frag - co16 * (KW * NC32);
    int k = rem / NC32, ci32 = rem - k * NC32;
    int co = co16 * 16 + (lane & 15);
    int ci = ci32 * 32 + (lane >> 4) * 8;
    short8 v;
#pragma unroll
    for (int j = 0; j < 8; j++) {
        float f = 0.f;
        if (co < COUT && ci + j < CIN) f = w[((size_t)co * CIN + ci + j) * KW + k];
        v[j] = f2bf(f);
    }
    *(short8*)(wp + (size_t)frag * 512 + lane * 8) = v;
}

// ---------------------------------------------------------------------------
// addspkT with inlined speaker projection:
// in fp32 [b][C][T] + (g[b]·w_spk[c] + b_spk[c]) -> out bf16 [b][T][C]
// ---------------------------------------------------------------------------
template <int C, int T>
__device__ __forceinline__ void addspkT_body(const float* __restrict__ in,
                                             const float* __restrict__ g,
                                             const float* __restrict__ w_spk,
                                             const float* __restrict__ b_spk,
                                             short* __restrict__ outT,
                                             float* sm, int bx, int by, int b) {
    float* spkS = sm;          // 32
    float* S = sm + 32;        // 32*65
    const int t0 = bx * 64, c0 = by * 32;
    const int tid = threadIdx.x;
    // inline spk: 8 threads per channel
    int cl = tid >> 3, part = tid & 7;
    int c = c0 + cl;
    float s = 0.f;
    if (c < C) {
        const float* wr = w_spk + (size_t)c * GD;
        const float* gr = g + b * GD;
        int j0 = part * 32;
#pragma unroll
        for (int j = 0; j < 32; j++) s += gr[j0 + j] * wr[j0 + j];
    }
    s += __shfl_xor(s, 1, 64); s += __shfl_xor(s, 2, 64); s += __shfl_xor(s, 4, 64);
    if (part == 0) spkS[cl] = s + ((c < C) ? b_spk[c] : 0.f);
    __syncthreads();
    for (int i = tid; i < 32 * 64; i += 256) {
        int cll = i >> 6, tl = i & 63;
        int gc = c0 + cll, gt = t0 + tl;
        float v = 0.f;
        if (gc < C && gt < T) v = in[((size_t)b * C + gc) * T + gt] + spkS[cll];
        S[cll * 65 + tl] = v;
    }
    __syncthreads();
    for (int i = tid; i < 64 * 32; i += 256) {
        int tl = i >> 5, cll = i & 31;
        int gt = t0 + tl, gc = c0 + cll;
        if (gc < C && gt < T) outT[((size_t)b * T + gt) * C + gc] = f2bf(S[cll * 65 + tl]);
    }
}

// ---------------------------------------------------------------------------
// P: one dispatch for all prep (weight packs + speaker-add transposes)
// ---------------------------------------------------------------------------
__global__ __launch_bounds__(256) void prep_kernel(
    const float* __restrict__ keys, const float* __restrict__ queries, const float* __restrict__ g,
    const float* __restrict__ wk1, const float* __restrict__ wq1, const float* __restrict__ wk2,
    const float* __restrict__ wq2, const float* __restrict__ wq3,
    const float* __restrict__ w_kspk, const float* __restrict__ b_kspk,
    const float* __restrict__ w_qspk, const float* __restrict__ b_qspk,
    short* __restrict__ wk1p, short* __restrict__ wq1p, short* __restrict__ wk2p,
    short* __restrict__ wq2p, short* __restrict__ wq3p,
    short* __restrict__ xkT, short* __restrict__ xqT) {
    __shared__ float sm[32 + 32 * 65];
    int bid = blockIdx.x;
    if (bid < 768) { wpack_body<C2T, CT, 3, C2T, CT>(wk1, wk1p, bid); return; }
    bid -= 768;
    if (bid < 27) { wpack_body<C2S, CS, 3, 192, 96>(wq1, wq1p, bid); return; }
    bid -= 27;
    if (bid < 40) { wpack_body<CA, C2T, 1, 80, 1024>(wk2, wk2p, bid); return; }
    bid -= 40;
    if (bid < 7) { wpack_body<CA, C2S, 1, 80, 160>(wq2, wq2p, bid); return; }
    bid -= 7;
    if (bid < 4) { wpack_body<CA, CS, 1, 80, 96>(wq3, wq3p, bid); return; }
    bid -= 4;
    if (bid < 1024) {
        int bx = bid & 3, by = (bid >> 2) & 15, b = bid >> 6;
        addspkT_body<CT, T2>(keys, g, w_kspk, b_kspk, xkT, sm, bx, by, b);
        return;
    }
    bid -= 1024;
    {
        int bx = bid & 15, by = (bid >> 4) % 3, b = bid / 48;
        addspkT_body<CS, T1>(queries, g, w_qspk, b_qspk, xqT, sm, bx, by, b);
    }
}

// ---------------------------------------------------------------------------
// conv3-as-GEMM body, W from global (A-frag layout), X in LDS (dbuf + reg prefetch)
// Block: 64co x 128t, 4 t-stacked waves (each 64co x 32t).  16x16x32 bf16 MFMA:
//   A lane m=l16(co), k=quad*8+j;  B lane n=l16(t), k=quad*8+j
//   D lane reg r: row(co)=quad*4+r, col(t)=l16   (validated rounds 3-6)
// ---------------------------------------------------------------------------
template <int CIN, int COUT, int T, int KW, bool RELU, int CICH, int NC32T>
__device__ __forceinline__ void conv_body(const short* __restrict__ xT,
                                          const short* __restrict__ wp,
                                          const float* __restrict__ bias,
                                          short* __restrict__ outT,
                                          short* Xs, int bx, int by, int b) {
    constexpr int TT = 128, COT = 64;
    constexpr int PAD = KW / 2;
    constexpr int XROWS = TT + KW - 1;
    constexpr int PITCH = CICH + 8;
    constexpr int NPC = CICH / 8;
    constexpr int NC32 = CICH / 32;
    constexpr int CINP = NC32T * 32;
    constexpr int NCHK = CINP / CICH;
    constexpr int NPIECE = XROWS * NPC;
    constexpr int NLD = (NPIECE + 255) / 256;

    const int t0 = bx * TT, co0 = by * COT;
    const int tid = threadIdx.x, wave = tid >> 6, lane = tid & 63;
    const int quad = lane >> 4, l16 = lane & 15;
    const int wt = wave * 32;
    const int co16_0 = co0 >> 4;
    const short* xb = xT + (size_t)b * T * CIN;

    floatx4 acc[4][2];
#pragma unroll
    for (int mi = 0; mi < 4; mi++)
#pragma unroll
        for (int ni = 0; ni < 2; ni++) acc[mi][ni] = (floatx4){0.f, 0.f, 0.f, 0.f};

    for (int i = tid; i < NPIECE; i += 256) {
        int r = i / NPC, p = i - r * NPC;
        int t = t0 + r - PAD, ci = p * 8;
        uint4 v = {0u, 0u, 0u, 0u};
        if ((unsigned)t < (unsigned)T && ci + 8 <= CIN)
            v = *(const uint4*)(xb + (size_t)t * CIN + ci);
        *(uint4*)(Xs + r * PITCH + p * 8) = v;
    }
    __syncthreads();

    for (int kc = 0; kc < NCHK; kc++) {
        uint4 tmp[NLD];
        if (NCHK > 1 && kc + 1 < NCHK) {
            int ci0n = (kc + 1) * CICH;
#pragma unroll
            for (int ld = 0; ld < NLD; ld++) {
                int i = tid + ld * 256;
                tmp[ld] = (uint4){0u, 0u, 0u, 0u};
                if (i < NPIECE) {
                    int r = i / NPC, p = i - r * NPC;
                    int t = t0 + r - PAD, ci = ci0n + p * 8;
                    if ((unsigned)t < (unsigned)T && ci + 8 <= CIN)
                        tmp[ld] = *(const uint4*)(xb + (size_t)t * CIN + ci);
                }
            }
        }
        const short* Xb = Xs + (NCHK > 1 ? (kc & 1) : 0) * XROWS * PITCH;
#pragma unroll
        for (int k = 0; k < KW; k++) {
#pragma unroll
            for (int kk = 0; kk < NC32; kk++) {
                int ci32 = kc * NC32 + kk;
                short8 a[4];
#pragma unroll
                for (int mi = 0; mi < 4; mi++)
                    a[mi] = *(const short8*)(wp +
                        ((size_t)((co16_0 + mi) * KW + k) * NC32T + ci32) * 512 + lane * 8);
#pragma unroll
                for (int ni = 0; ni < 2; ni++) {
                    short8 bb = *(const short8*)(Xb + (wt + ni * 16 + l16 + k) * PITCH +
                                                 kk * 32 + quad * 8);
#pragma unroll
                    for (int mi = 0; mi < 4; mi++)
                        acc[mi][ni] = __builtin_amdgcn_mfma_f32_16x16x32_bf16(a[mi], bb,
                                                                              acc[mi][ni], 0, 0, 0);
                }
            }
        }
        if (NCHK > 1 && kc + 1 < NCHK) {
            short* Xn = Xs + ((kc + 1) & 1) * XROWS * PITCH;
#pragma unroll
            for (int ld = 0; ld < NLD; ld++) {
                int i = tid + ld * 256;
                if (i < NPIECE) {
                    int r = i / NPC, p = i - r * NPC;
                    *(uint4*)(Xn + r * PITCH + p * 8) = tmp[ld];
                }
            }
            __syncthreads();
        }
    }
#pragma unroll
    for (int mi = 0; mi < 4; mi++) {
        int cb = co0 + mi * 16 + quad * 4;
        if (cb < COUT) {
            float4 bv = *(const float4*)(bias + cb);
#pragma unroll
            for (int ni = 0; ni < 2; ni++) {
                int t = t0 + wt + ni * 16 + l16;
                if (t < T) {
                    float v0 = acc[mi][ni][0] + bv.x, v1 = acc[mi][ni][1] + bv.y;
                    float v2 = acc[mi][ni][2] + bv.z, v3 = acc[mi][ni][3] + bv.w;
                    if (RELU) {
                        v0 = fmaxf(v0, 0.f); v1 = fmaxf(v1, 0.f);
                        v2 = fmaxf(v2, 0.f); v3 = fmaxf(v3, 0.f);
                    }
                    ushort4 o;
                    o.x = (unsigned short)f2bf(v0); o.y = (unsigned short)f2bf(v1);
                    o.z = (unsigned short)f2bf(v2); o.w = (unsigned short)f2bf(v3);
                    *(ushort4*)(outT + ((size_t)b * T + t) * COUT + cb) = o;
                }
            }
        }
    }
}

// C: key conv3 (512 blocks) + query conv3 (384 blocks) in one dispatch
__global__ __launch_bounds__(256, 2) void conv_kernel(
    const short* __restrict__ xkT, const short* __restrict__ wk1p,
    const float* __restrict__ bk1, short* __restrict__ kh1T,
    const short* __restrict__ xqT, const short* __restrict__ wq1p,
    const float* __restrict__ bq1, short* __restrict__ qh1T) {
    __shared__ short sm[18720];   // max(key 2*130*72, query 130*104)
    int bid = blockIdx.x;
    if (bid < 512) {
        int bx = bid & 1, by = (bid >> 1) & 15, b = bid >> 5;
        conv_body<CT, C2T, T2, 3, true, 64, 16>(xkT, wk1p, bk1, kh1T, sm, bx, by, b);
    } else {
        int r = bid - 512;
        int bx = r & 7, by = (r >> 3) % 3, b = r / 24;
        conv_body<CS, C2S, T1, 3, true, 96, 3>(xqT, wq1p, bq1, qh1T, sm, bx, by, b);
    }
}

// ---------------------------------------------------------------------------
// key 1x1: full-K GEMM (K=1024), W from global frags, X dbuf in LDS
// ---------------------------------------------------------------------------
__device__ __forceinline__ void kgemm_body(const short* __restrict__ xT,
                                           const short* __restrict__ wp,
                                           const float* __restrict__ bias,
                                           short* __restrict__ outT, short* sm, int bid) {
    constexpr int K = 1024, KCH = 128, PITCH = 136, NPC = 16, NCHK = 8;
    const int n0 = bid * 64;
    const int tid = threadIdx.x, wave = tid >> 6, lane = tid & 63;
    const int quad = lane >> 4, l16 = lane & 15;
    floatx4 acc[5];
#pragma unroll
    for (int mi = 0; mi < 5; mi++) acc[mi] = (floatx4){0.f, 0.f, 0.f, 0.f};

    for (int i = tid; i < 64 * NPC; i += 256) {
        int r = i / NPC, p = i - r * NPC;
        *(uint4*)(sm + r * PITCH + p * 8) = *(const uint4*)(xT + (size_t)(n0 + r) * K + p * 8);
    }
    __syncthreads();
    for (int kc = 0; kc < NCHK; kc++) {
        uint4 tmp[4];
        if (kc + 1 < NCHK) {
            int ci0 = (kc + 1) * KCH;
#pragma unroll
            for (int ld = 0; ld < 4; ld++) {
                int i = tid + ld * 256;
                int r = i / NPC, p = i - r * NPC;
                tmp[ld] = *(const uint4*)(xT + (size_t)(n0 + r) * K + ci0 + p * 8);
            }
        }
        const short* Xb = sm + (kc & 1) * 64 * PITCH;
#pragma unroll
        for (int kk = 0; kk < 4; kk++) {
            int ci32 = kc * 4 + kk;
            short8 bb = *(const short8*)(Xb + (wave * 16 + l16) * PITCH + kk * 32 + quad * 8);
#pragma unroll
            for (int mi = 0; mi < 5; mi++) {
                short8 a = *(const short8*)(wp + ((size_t)(mi * 32 + ci32)) * 512 + lane * 8);
                acc[mi] = __builtin_amdgcn_mfma_f32_16x16x32_bf16(a, bb, acc[mi], 0, 0, 0);
            }
        }
        if (kc + 1 < NCHK) {
            short* Xn = sm + ((kc + 1) & 1) * 64 * PITCH;
#pragma unroll
            for (int ld = 0; ld < 4; ld++) {
                int i = tid + ld * 256;
                int r = i / NPC, p = i - r * NPC;
                *(uint4*)(Xn + r * PITCH + p * 8) = tmp[ld];
            }
            __syncthreads();
        }
    }
    int n = n0 + wave * 16 + l16;
#pragma unroll
    for (int mi = 0; mi < 5; mi++) {
        int cb = mi * 16 + quad * 4;
        float4 bv = *(const float4*)(bias + cb);
        ushort4 o;
        o.x = (unsigned short)f2bf(acc[mi][0] + bv.x);
        o.y = (unsigned short)f2bf(acc[mi][1] + bv.y);
        o.z = (unsigned short)f2bf(acc[mi][2] + bv.z);
        o.w = (unsigned short)f2bf(acc[mi][3] + bv.w);
        *(ushort4*)(outT + (size_t)n * CA + cb) = o;
    }
}

// fused query conv2(relu)+conv3, W from global frags
__device__ __forceinline__ void qconv23_body(const short* __restrict__ h1,
                                             const short* __restrict__ w2p,
                                             const float* __restrict__ b2,
                                             const short* __restrict__ w3p,
                                             const float* __restrict__ b3,
                                             short* __restrict__ outT, short* sm, int bid) {
    constexpr int K1 = 160, P1 = 168, NPC1 = 20, P3 = 104;
    short* Xs = sm;            // 64*168
    short* Hs = sm + 64 * P1;  // 64*104
    const int n0 = bid * 64;
    const int tid = threadIdx.x, wave = tid >> 6, lane = tid & 63;
    const int quad = lane >> 4, l16 = lane & 15;

    for (int i = tid; i < 64 * NPC1; i += 256) {
        int r = i / NPC1, p = i - r * NPC1;
        *(uint4*)(Xs + r * P1 + p * 8) = *(const uint4*)(h1 + (size_t)(n0 + r) * K1 + p * 8);
    }
    if (tid < 128) *(uint4*)(Hs + (tid >> 1) * P3 + 80 + (tid & 1) * 8) = (uint4){0u, 0u, 0u, 0u};
    __syncthreads();

    floatx4 acc[5];
#pragma unroll
    for (int mi = 0; mi < 5; mi++) acc[mi] = (floatx4){0.f, 0.f, 0.f, 0.f};
#pragma unroll
    for (int kk = 0; kk < 5; kk++) {
        short8 bb = *(const short8*)(Xs + (wave * 16 + l16) * P1 + kk * 32 + quad * 8);
#pragma unroll
        for (int mi = 0; mi < 5; mi++) {
            short8 a = *(const short8*)(w2p + ((size_t)(mi * 5 + kk)) * 512 + lane * 8);
            acc[mi] = __builtin_amdgcn_mfma_f32_16x16x32_bf16(a, bb, acc[mi], 0, 0, 0);
        }
    }
#pragma unroll
    for (int mi = 0; mi < 5; mi++) {
        int cb = mi * 16 + quad * 4;
        float4 bv = *(const float4*)(b2 + cb);
        ushort4 o;
        o.x = (unsigned short)f2bf(fmaxf(acc[mi][0] + bv.x, 0.f));
        o.y = (unsigned short)f2bf(fmaxf(acc[mi][1] + bv.y, 0.f));
        o.z = (unsigned short)f2bf(fmaxf(acc[mi][2] + bv.z, 0.f));
        o.w = (unsigned short)f2bf(fmaxf(acc[mi][3] + bv.w, 0.f));
        *(ushort4*)(Hs + (wave * 16 + l16) * P3 + cb) = o;
    }
    __syncthreads();

    floatx4 acc3[5];
#pragma unroll
    for (int mi = 0; mi < 5; mi++) acc3[mi] = (floatx4){0.f, 0.f, 0.f, 0.f};
#pragma unroll
    for (int kk = 0; kk < 3; kk++) {
        short8 bb = *(const short8*)(Hs + (wave * 16 + l16) * P3 + kk * 32 + quad * 8);
#pragma unroll
        for (int mi = 0; mi < 5; mi++) {
            short8 a = *(const short8*)(w3p + ((size_t)(mi * 3 + kk)) * 512 + lane * 8);
            acc3[mi] = __builtin_amdgcn_mfma_f32_16x16x32_bf16(a, bb, acc3[mi], 0, 0, 0);
        }
    }
    int n = n0 + wave * 16 + l16;
#pragma unroll
    for (int mi = 0; mi < 5; mi++) {
        int cb = mi * 16 + quad * 4;
        float4 bv = *(const float4*)(b3 + cb);
        ushort4 o;
        o.x = (unsigned short)f2bf(acc3[mi][0] + bv.x);
        o.y = (unsigned short)f2bf(acc3[mi][1] + bv.y);
        o.z = (unsigned short)f2bf(acc3[mi][2] + bv.z);
        o.w = (unsigned short)f2bf(acc3[mi][3] + bv.w);
        *(ushort4*)(outT + (size_t)n * CA + cb) = o;
    }
}

// G: key 1x1 GEMM (50 blocks) + fused query conv2+conv3 (250 blocks)
__global__ __launch_bounds__(256, 2) void gemm_kernel(
    const short* __restrict__ kh1T, const short* __restrict__ wk2p,
    const float* __restrict__ bk2, short* __restrict__ k_encT,
    const short* __restrict__ qh1T, const short* __restrict__ wq2p,
    const float* __restrict__ bq2, const short* __restrict__ wq3p,
    const float* __restrict__ bq3, short* __restrict__ q_encT) {
    __shared__ short sm[17408];   // gemm: 2*64*136; qconv23: 64*168+64*104
    int bid = blockIdx.x;
    if (bid < 50) kgemm_body(kh1T, wk2p, bk2, k_encT, sm, bid);
    else qconv23_body(qh1T, wq2p, bq2, wq3p, bq3, q_encT, sm, bid - 50);
}

// ---------------------------------------------------------------------------
// attention: block = (64 t1) x b.  QK^T via MFMA; q^2 cancels; k^2 in-block.
// ---------------------------------------------------------------------------
__device__ __forceinline__ float rmax16(float v) {
#pragma unroll
    for (int o = 1; o < 16; o <<= 1) v = fmaxf(v, __shfl_xor(v, o, 64));
    return v;
}
__device__ __forceinline__ float rsum16(float v) {
#pragma unroll
    for (int o = 1; o < 16; o <<= 1) v += __shfl_xor(v, o, 64);
    return v;
}

__global__ __launch_bounds__(256) void attn_kernel(const short* __restrict__ q_encT,
                                                   const short* __restrict__ k_encT,
                                                   const float* __restrict__ prior,
                                                   const int* __restrict__ mask,
                                                   float* __restrict__ out_attn,
                                                   float* __restrict__ out_logp) {
    constexpr int T2R = 208, PITCH = 104, NPC = 12;
    __shared__ short Kt[T2R * PITCH];
    __shared__ short Qs[64 * PITCH];
    __shared__ float k2s[T2R];
    __shared__ int msk[T2R];
    const int t10 = blockIdx.x * 64, b = blockIdx.y;
    const int tid = threadIdx.x;
    const int wave = tid >> 6, lane = tid & 63;
    const int quad = lane >> 4, l16 = lane & 15;

    for (int i = tid; i < T2R * NPC; i += 256) {
        int r = i / NPC, p = i - r * NPC;
        uint4 v = {0u, 0u, 0u, 0u};
        if (r < T2 && p < 10) v = *(const uint4*)(k_encT + ((size_t)b * T2 + r) * CA + p * 8);
        *(uint4*)(Kt + r * PITCH + p * 8) = v;
    }
    for (int i = tid; i < 64 * NPC; i += 256) {
        int r = i / NPC, p = i - r * NPC;
        int t1 = t10 + r;
        uint4 v = {0u, 0u, 0u, 0u};
        if (t1 < T1 && p < 10) v = *(const uint4*)(q_encT + ((size_t)b * T1 + t1) * CA + p * 8);
        *(uint4*)(Qs + r * PITCH + p * 8) = v;
    }
    if (tid < T2R) msk[tid] = (tid < T2) ? mask[b * T2 + tid] : 0;
    __syncthreads();
    for (int r = tid; r < T2R; r += 256) {
        float s = 0.f;
        for (int p = 0; p < NPC; p++) {
            short8 v = *(const short8*)(Kt + r * PITCH + p * 8);
#pragma unroll
            for (int j = 0; j < 8; j++) { float f = bf2f(v[j]); s += f * f; }
        }
        k2s[r] = s;
    }
    __syncthreads();

    floatx4 acc[13];
#pragma unroll
    for (int n = 0; n < 13; n++) acc[n] = (floatx4){0.f, 0.f, 0.f, 0.f};
#pragma unroll
    for (int kk = 0; kk < 3; kk++) {
        short8 a = *(const short8*)(Qs + (wave * 16 + l16) * PITCH + kk * 32 + quad * 8);
#pragma unroll
        for (int n = 0; n < 13; n++) {
            short8 bb = *(const short8*)(Kt + (n * 16 + l16) * PITCH + kk * 32 + quad * 8);
            acc[n] = __builtin_amdgcn_mfma_f32_16x16x32_bf16(a, bb, acc[n], 0, 0, 0);
        }
    }

#pragma unroll
    for (int r = 0; r < 4; r++) {
        int t1 = t10 + wave * 16 + quad * 4 + r;
        bool t1ok = t1 < T1;
        float s[13];
        float mx = -INFINITY;
#pragma unroll
        for (int n = 0; n < 13; n++) {
            int t2 = n * 16 + l16;
            float sv = -INFINITY;
            if (t2 < T2) sv = -TEMP_F * (k2s[t2] - 2.f * acc[n][r]);
            s[n] = sv;
            mx = fmaxf(mx, sv);
        }
        float m = rmax16(mx);
        float sume = 0.f;
#pragma unroll
        for (int n = 0; n < 13; n++) sume += (s[n] == -INFINITY) ? 0.f : __expf(s[n] - m);
        float logZ = __logf(rsum16(sume));
        float mx2 = -INFINITY;
#pragma unroll
        for (int n = 0; n < 13; n++) {
            int t2 = n * 16 + l16;
            float pr = 1.f;
            if (t1ok && t2 < T2) pr = prior[((size_t)b * T1 + t1) * T2 + t2];
            float lp = (t2 < T2) ? (s[n] - m - logZ + __logf(pr + 1e-8f)) : -INFINITY;
            s[n] = lp;
            float ms = (t2 < T2 && msk[t2] != 0) ? lp : -INFINITY;
            mx2 = fmaxf(mx2, ms);
        }
        float m2 = rmax16(mx2);
        float sume2 = 0.f;
        float e2v[13];
#pragma unroll
        for (int n = 0; n < 13; n++) {
            int t2 = n * 16 + l16;
            float ms = (t2 < T2 && msk[t2] != 0) ? s[n] : -INFINITY;
            float e = (ms == -INFINITY) ? 0.f : __expf(ms - m2);
            e2v[n] = e;
            sume2 += e;
        }
        float Z2 = rsum16(sume2);
        if (t1ok) {
#pragma unroll
            for (int n = 0; n < 13; n++) {
                int t2 = n * 16 + l16;
                if (t2 < T2) {
                    size_t o = ((size_t)b * T1 + t1) * T2 + t2;
                    out_attn[o] = e2v[n] / Z2;
                    out_logp[o] = s[n];
                }
            }
        }
    }
}

// ---------------------------------------------------------------------------
extern "C" void kernel_launch(void* const* d_in, const int* in_sizes, int n_in,
                              void* d_out, int out_size, void* d_ws, size_t ws_size,
                              hipStream_t stream) {
    const float* queries = (const float*)d_in[0];
    const float* keys    = (const float*)d_in[1];
    const int*   mask    = (const int*)d_in[2];
    const float* prior   = (const float*)d_in[3];
    const float* g       = (const float*)d_in[4];
    const float* wk1 = (const float*)d_in[5];
    const float* bk1 = (const float*)d_in[6];
    const float* wk2 = (const float*)d_in[7];
    const float* bk2 = (const float*)d_in[8];
    const float* wq1 = (const float*)d_in[9];
    const float* bq1 = (const float*)d_in[10];
    const float* wq2 = (const float*)d_in[11];
    const float* bq2 = (const float*)d_in[12];
    const float* wq3 = (const float*)d_in[13];
    const float* bq3 = (const float*)d_in[14];
    const float* w_kspk = (const float*)d_in[15];
    const float* b_kspk = (const float*)d_in[16];
    const float* w_qspk = (const float*)d_in[17];
    const float* b_qspk = (const float*)d_in[18];

    // ---- workspace layout (shorts) ----
    short* wsS   = (short*)d_ws;
    short* xkT   = wsS;                              // 16x200x512      -> 1,638,400
    short* xqT   = wsS + 1638400;                    // 16x1000x80      -> 2,918,400
    short* wk1p  = wsS + 2918400;                    // 3072 frags      -> 4,491,264
    short* wq1p  = wsS + 4491264;                    // 108 frags       -> 4,546,560
    short* wk2p  = wsS + 4546560;                    // 160 frags       -> 4,628,480
    short* wq2p  = wsS + 4628480;                    // 25 frags        -> 4,641,280
    short* wq3p  = wsS + 4641280;                    // 15 frags        -> 4,648,960
    short* k_encT = wsS + 4648960;                   // 3200x80         -> 4,904,960
    short* q_encT = wsS + 4904960;                   // 16000x80        -> 6,184,960 (12.4 MB)
    // hidden layers in d_out (consumed before attn overwrites):
    short* doS  = (short*)d_out;
    short* kh1T = doS;                               // 3200x1024 (6.55 MB)
    short* qh1T = doS + 3276800;                     // 16000x160 (5.12 MB)

    // P: all prep in one dispatch (2638 blocks)
    prep_kernel<<<dim3(2638), dim3(256), 0, stream>>>(
        keys, queries, g, wk1, wq1, wk2, wq2, wq3,
        w_kspk, b_kspk, w_qspk, b_qspk,
        wk1p, wq1p, wk2p, wq2p, wq3p, xkT, xqT);
    // C: both k=3 convs in one dispatch (896 blocks)
    conv_kernel<<<dim3(896), dim3(256), 0, stream>>>(xkT, wk1p, bk1, kh1T,
                                                     xqT, wq1p, bq1, qh1T);
    // G: key 1x1 GEMM + fused query conv2/conv3 (300 blocks)
    gemm_kernel<<<dim3(300), dim3(256), 0, stream>>>(kh1T, wk2p, bk2, k_encT,
                                                     qh1T, wq2p, bq2, wq3p, bq3, q_encT);
    // A: attention
    float* out_attn = (float*)d_out;
    float* out_logp = out_attn + (size_t)NB * T1 * T2;
    attn_kernel<<<dim3(16, NB), dim3(256), 0, stream>>>(q_encT, k_encT, prior, mask,
                                                        out_attn, out_logp);
}

// Round 8
// 190.498 us; speedup vs baseline: 7.2620x; 1.1085x over previous
//
#include <hip/hip_runtime.h>
#include <hip/hip_bf16.h>
#include <math.h>

#define NB 16      // batch
#define CS 80      // spec channels
#define T1 1000    // mel frames
#define CT 512     // text channels
#define T2 200     // phonemes
#define CA 80      // attn channels
#define GD 256     // speaker dim
#define C2T 1024   // 2*Ct
#define C2S 160    // 2*Cs
#define TEMP_F 0.0005f
#define ENC_STR 96 // padded row stride for k_encT/q_encT (zero-filled 80..95)

typedef __attribute__((ext_vector_type(8))) short short8;
typedef __attribute__((ext_vector_type(4))) float floatx4;

// fp32 -> bf16 bits, round-to-nearest-even
__device__ __forceinline__ short f2bf(float x) {
    unsigned u = __builtin_bit_cast(unsigned, x);
    unsigned r = (u + 0x7fffu + ((u >> 16) & 1u)) >> 16;
    return (short)r;
}

// ---------------------------------------------------------------------------
// weight pack into MFMA A-fragment-major layout:
//   wp[((co16*KW + k)*NC32 + ci32)*512 + lane*8 + j]
//   co = co16*16 + (lane&15), ci = ci32*32 + (lane>>4)*8 + j
// ---------------------------------------------------------------------------
template <int COUT, int CIN, int KW, int COP, int CINP>
__device__ __forceinline__ void wpack_body(const float* __restrict__ w,
                                           short* __restrict__ wp, int bid) {
    constexpr int NC32 = CINP / 32;
    constexpr int NFRAG = (COP / 16) * KW * NC32;
    int gid = bid * 256 + threadIdx.x;
    int frag = gid >> 6, lane = gid & 63;
    if (frag >= NFRAG) return;
    int co16 = frag / (KW * NC32), rem = frag - co16 * (KW * NC32);
    int k = rem / NC32, ci32 = rem - k * NC32;
    int co = co16 * 16 + (lane & 15);
    int ci = ci32 * 32 + (lane >> 4) * 8;
    short8 v;
#pragma unroll
    for (int j = 0; j < 8; j++) {
        float f = 0.f;
        if (co < COUT && ci + j < CIN) f = w[((size_t)co * CIN + ci + j) * KW + k];
        v[j] = f2bf(f);
    }
    *(short8*)(wp + (size_t)frag * 512 + lane * 8) = v;
}

// ---------------------------------------------------------------------------
// addspkT with inlined speaker projection:
// in fp32 [b][C][T] + (g[b]·w_spk[c] + b_spk[c]) -> out bf16 [b][T][C]
// ---------------------------------------------------------------------------
template <int C, int T>
__device__ __forceinline__ void addspkT_body(const float* __restrict__ in,
                                             const float* __restrict__ g,
                                             const float* __restrict__ w_spk,
                                             const float* __restrict__ b_spk,
                                             short* __restrict__ outT,
                                             float* sm, int bx, int by, int b) {
    float* spkS = sm;          // 32
    float* S = sm + 32;        // 32*65
    const int t0 = bx * 64, c0 = by * 32;
    const int tid = threadIdx.x;
    int cl = tid >> 3, part = tid & 7;
    int c = c0 + cl;
    float s = 0.f;
    if (c < C) {
        const float* wr = w_spk + (size_t)c * GD;
        const float* gr = g + b * GD;
        int j0 = part * 32;
#pragma unroll
        for (int j = 0; j < 32; j++) s += gr[j0 + j] * wr[j0 + j];
    }
    s += __shfl_xor(s, 1, 64); s += __shfl_xor(s, 2, 64); s += __shfl_xor(s, 4, 64);
    if (part == 0) spkS[cl] = s + ((c < C) ? b_spk[c] : 0.f);
    __syncthreads();
    for (int i = tid; i < 32 * 64; i += 256) {
        int cll = i >> 6, tl = i & 63;
        int gc = c0 + cll, gt = t0 + tl;
        float v = 0.f;
        if (gc < C && gt < T) v = in[((size_t)b * C + gc) * T + gt] + spkS[cll];
        S[cll * 65 + tl] = v;
    }
    __syncthreads();
    for (int i = tid; i < 64 * 32; i += 256) {
        int tl = i >> 5, cll = i & 31;
        int gt = t0 + tl, gc = c0 + cll;
        if (gc < C && gt < T) outT[((size_t)b * T + gt) * C + gc] = f2bf(S[cll * 65 + tl]);
    }
}

// ---------------------------------------------------------------------------
// P: one dispatch for all prep
// ---------------------------------------------------------------------------
__global__ __launch_bounds__(256) void prep_kernel(
    const float* __restrict__ keys, const float* __restrict__ queries, const float* __restrict__ g,
    const float* __restrict__ wk1, const float* __restrict__ wq1, const float* __restrict__ wk2,
    const float* __restrict__ wq2, const float* __restrict__ wq3,
    const float* __restrict__ w_kspk, const float* __restrict__ b_kspk,
    const float* __restrict__ w_qspk, const float* __restrict__ b_qspk,
    short* __restrict__ wk1p, short* __restrict__ wq1p, short* __restrict__ wk2p,
    short* __restrict__ wq2p, short* __restrict__ wq3p,
    short* __restrict__ xkT, short* __restrict__ xqT) {
    __shared__ float sm[32 + 32 * 65];
    int bid = blockIdx.x;
    if (bid < 768) { wpack_body<C2T, CT, 3, C2T, CT>(wk1, wk1p, bid); return; }
    bid -= 768;
    if (bid < 27) { wpack_body<C2S, CS, 3, 192, 96>(wq1, wq1p, bid); return; }
    bid -= 27;
    if (bid < 40) { wpack_body<CA, C2T, 1, 80, 1024>(wk2, wk2p, bid); return; }
    bid -= 40;
    if (bid < 7) { wpack_body<CA, C2S, 1, 80, 160>(wq2, wq2p, bid); return; }
    bid -= 7;
    if (bid < 4) { wpack_body<CA, CS, 1, 80, 96>(wq3, wq3p, bid); return; }
    bid -= 4;
    if (bid < 1024) {
        int bx = bid & 3, by = (bid >> 2) & 15, b = bid >> 6;
        addspkT_body<CT, T2>(keys, g, w_kspk, b_kspk, xkT, sm, bx, by, b);
        return;
    }
    bid -= 1024;
    {
        int bx = bid & 15, by = (bid >> 4) % 3, b = bid / 48;
        addspkT_body<CS, T1>(queries, g, w_qspk, b_qspk, xqT, sm, bx, by, b);
    }
}

// ---------------------------------------------------------------------------
// conv3-as-GEMM body, W from global (A-frag layout), X in LDS (dbuf + reg prefetch)
// 16x16x32 bf16 MFMA: A lane m=l16(co), k=quad*8+j; B lane n=l16(t), k=quad*8+j
//   D lane reg r: row(co)=quad*4+r, col(t)=l16   (validated rounds 3-7)
// ---------------------------------------------------------------------------
template <int CIN, int COUT, int T, int KW, bool RELU, int CICH, int NC32T>
__device__ __forceinline__ void conv_body(const short* __restrict__ xT,
                                          const short* __restrict__ wp,
                                          const float* __restrict__ bias,
                                          short* __restrict__ outT,
                                          short* Xs, int bx, int by, int b) {
    constexpr int TT = 128, COT = 64;
    constexpr int PAD = KW / 2;
    constexpr int XROWS = TT + KW - 1;
    constexpr int PITCH = CICH + 8;
    constexpr int NPC = CICH / 8;
    constexpr int NC32 = CICH / 32;
    constexpr int CINP = NC32T * 32;
    constexpr int NCHK = CINP / CICH;
    constexpr int NPIECE = XROWS * NPC;
    constexpr int NLD = (NPIECE + 255) / 256;

    const int t0 = bx * TT, co0 = by * COT;
    const int tid = threadIdx.x, wave = tid >> 6, lane = tid & 63;
    const int quad = lane >> 4, l16 = lane & 15;
    const int wt = wave * 32;
    const int co16_0 = co0 >> 4;
    const short* xb = xT + (size_t)b * T * CIN;

    floatx4 acc[4][2];
#pragma unroll
    for (int mi = 0; mi < 4; mi++)
#pragma unroll
        for (int ni = 0; ni < 2; ni++) acc[mi][ni] = (floatx4){0.f, 0.f, 0.f, 0.f};

    for (int i = tid; i < NPIECE; i += 256) {
        int r = i / NPC, p = i - r * NPC;
        int t = t0 + r - PAD, ci = p * 8;
        uint4 v = {0u, 0u, 0u, 0u};
        if ((unsigned)t < (unsigned)T && ci + 8 <= CIN)
            v = *(const uint4*)(xb + (size_t)t * CIN + ci);
        *(uint4*)(Xs + r * PITCH + p * 8) = v;
    }
    __syncthreads();

    for (int kc = 0; kc < NCHK; kc++) {
        uint4 tmp[NLD];
        if (NCHK > 1 && kc + 1 < NCHK) {
            int ci0n = (kc + 1) * CICH;
#pragma unroll
            for (int ld = 0; ld < NLD; ld++) {
                int i = tid + ld * 256;
                tmp[ld] = (uint4){0u, 0u, 0u, 0u};
                if (i < NPIECE) {
                    int r = i / NPC, p = i - r * NPC;
                    int t = t0 + r - PAD, ci = ci0n + p * 8;
                    if ((unsigned)t < (unsigned)T && ci + 8 <= CIN)
                        tmp[ld] = *(const uint4*)(xb + (size_t)t * CIN + ci);
                }
            }
        }
        const short* Xb = Xs + (NCHK > 1 ? (kc & 1) : 0) * XROWS * PITCH;
#pragma unroll
        for (int k = 0; k < KW; k++) {
#pragma unroll
            for (int kk = 0; kk < NC32; kk++) {
                int ci32 = kc * NC32 + kk;
                short8 a[4];
#pragma unroll
                for (int mi = 0; mi < 4; mi++)
                    a[mi] = *(const short8*)(wp +
                        ((size_t)((co16_0 + mi) * KW + k) * NC32T + ci32) * 512 + lane * 8);
#pragma unroll
                for (int ni = 0; ni < 2; ni++) {
                    short8 bb = *(const short8*)(Xb + (wt + ni * 16 + l16 + k) * PITCH +
                                                 kk * 32 + quad * 8);
#pragma unroll
                    for (int mi = 0; mi < 4; mi++)
                        acc[mi][ni] = __builtin_amdgcn_mfma_f32_16x16x32_bf16(a[mi], bb,
                                                                              acc[mi][ni], 0, 0, 0);
                }
            }
        }
        if (NCHK > 1 && kc + 1 < NCHK) {
            short* Xn = Xs + ((kc + 1) & 1) * XROWS * PITCH;
#pragma unroll
            for (int ld = 0; ld < NLD; ld++) {
                int i = tid + ld * 256;
                if (i < NPIECE) {
                    int r = i / NPC, p = i - r * NPC;
                    *(uint4*)(Xn + r * PITCH + p * 8) = tmp[ld];
                }
            }
            __syncthreads();
        }
    }
#pragma unroll
    for (int mi = 0; mi < 4; mi++) {
        int cb = co0 + mi * 16 + quad * 4;
        if (cb < COUT) {
            float4 bv = *(const float4*)(bias + cb);
#pragma unroll
            for (int ni = 0; ni < 2; ni++) {
                int t = t0 + wt + ni * 16 + l16;
                if (t < T) {
                    float v0 = acc[mi][ni][0] + bv.x, v1 = acc[mi][ni][1] + bv.y;
                    float v2 = acc[mi][ni][2] + bv.z, v3 = acc[mi][ni][3] + bv.w;
                    if (RELU) {
                        v0 = fmaxf(v0, 0.f); v1 = fmaxf(v1, 0.f);
                        v2 = fmaxf(v2, 0.f); v3 = fmaxf(v3, 0.f);
                    }
                    ushort4 o;
                    o.x = (unsigned short)f2bf(v0); o.y = (unsigned short)f2bf(v1);
                    o.z = (unsigned short)f2bf(v2); o.w = (unsigned short)f2bf(v3);
                    *(ushort4*)(outT + ((size_t)b * T + t) * COUT + cb) = o;
                }
            }
        }
    }
}

// C: key conv3 (512 blocks) + query conv3 (384 blocks) in one dispatch
__global__ __launch_bounds__(256, 2) void conv_kernel(
    const short* __restrict__ xkT, const short* __restrict__ wk1p,
    const float* __restrict__ bk1, short* __restrict__ kh1T,
    const short* __restrict__ xqT, const short* __restrict__ wq1p,
    const float* __restrict__ bq1, short* __restrict__ qh1T) {
    __shared__ short sm[18720];
    int bid = blockIdx.x;
    if (bid < 512) {
        int bx = bid & 1, by = (bid >> 1) & 15, b = bid >> 5;
        conv_body<CT, C2T, T2, 3, true, 64, 16>(xkT, wk1p, bk1, kh1T, sm, bx, by, b);
    } else {
        int r = bid - 512;
        int bx = r & 7, by = (r >> 3) % 3, b = r / 24;
        conv_body<CS, C2S, T1, 3, true, 96, 3>(xqT, wq1p, bq1, qh1T, sm, bx, by, b);
    }
}

// ---------------------------------------------------------------------------
// key 1x1: full-K GEMM (K=1024), W from global frags, X dbuf in LDS.
// Emits k_encT with row stride ENC_STR (zero pad) + k2 per row.
// ---------------------------------------------------------------------------
__device__ __forceinline__ void kgemm_body(const short* __restrict__ xT,
                                           const short* __restrict__ wp,
                                           const float* __restrict__ bias,
                                           short* __restrict__ outT,
                                           float* __restrict__ k2ws,
                                           short* sm, int bid) {
    constexpr int K = 1024, KCH = 128, PITCH = 136, NPC = 16, NCHK = 8;
    const int n0 = bid * 64;
    const int tid = threadIdx.x, wave = tid >> 6, lane = tid & 63;
    const int quad = lane >> 4, l16 = lane & 15;
    floatx4 acc[5];
#pragma unroll
    for (int mi = 0; mi < 5; mi++) acc[mi] = (floatx4){0.f, 0.f, 0.f, 0.f};

    for (int i = tid; i < 64 * NPC; i += 256) {
        int r = i / NPC, p = i - r * NPC;
        *(uint4*)(sm + r * PITCH + p * 8) = *(const uint4*)(xT + (size_t)(n0 + r) * K + p * 8);
    }
    __syncthreads();
    for (int kc = 0; kc < NCHK; kc++) {
        uint4 tmp[4];
        if (kc + 1 < NCHK) {
            int ci0 = (kc + 1) * KCH;
#pragma unroll
            for (int ld = 0; ld < 4; ld++) {
                int i = tid + ld * 256;
                int r = i / NPC, p = i - r * NPC;
                tmp[ld] = *(const uint4*)(xT + (size_t)(n0 + r) * K + ci0 + p * 8);
            }
        }
        const short* Xb = sm + (kc & 1) * 64 * PITCH;
#pragma unroll
        for (int kk = 0; kk < 4; kk++) {
            int ci32 = kc * 4 + kk;
            short8 bb = *(const short8*)(Xb + (wave * 16 + l16) * PITCH + kk * 32 + quad * 8);
#pragma unroll
            for (int mi = 0; mi < 5; mi++) {
                short8 a = *(const short8*)(wp + ((size_t)(mi * 32 + ci32)) * 512 + lane * 8);
                acc[mi] = __builtin_amdgcn_mfma_f32_16x16x32_bf16(a, bb, acc[mi], 0, 0, 0);
            }
        }
        if (kc + 1 < NCHK) {
            short* Xn = sm + ((kc + 1) & 1) * 64 * PITCH;
#pragma unroll
            for (int ld = 0; ld < 4; ld++) {
                int i = tid + ld * 256;
                int r = i / NPC, p = i - r * NPC;
                *(uint4*)(Xn + r * PITCH + p * 8) = tmp[ld];
            }
            __syncthreads();
        }
    }
    int n = n0 + wave * 16 + l16;
    float sq = 0.f;
#pragma unroll
    for (int mi = 0; mi < 5; mi++) {
        int cb = mi * 16 + quad * 4;
        float4 bv = *(const float4*)(bias + cb);
        float v0 = acc[mi][0] + bv.x, v1 = acc[mi][1] + bv.y;
        float v2 = acc[mi][2] + bv.z, v3 = acc[mi][3] + bv.w;
        sq += v0 * v0 + v1 * v1 + v2 * v2 + v3 * v3;
        ushort4 o;
        o.x = (unsigned short)f2bf(v0); o.y = (unsigned short)f2bf(v1);
        o.z = (unsigned short)f2bf(v2); o.w = (unsigned short)f2bf(v3);
        *(ushort4*)(outT + (size_t)n * ENC_STR + cb) = o;
    }
    if (quad < 2) *(uint4*)(outT + (size_t)n * ENC_STR + 80 + quad * 8) = (uint4){0u, 0u, 0u, 0u};
    sq += __shfl_xor(sq, 16, 64);
    sq += __shfl_xor(sq, 32, 64);
    if (quad == 0) k2ws[n] = sq;
}

// fused query conv2(relu)+conv3, W from global frags; q_encT row stride ENC_STR
__device__ __forceinline__ void qconv23_body(const short* __restrict__ h1,
                                             const short* __restrict__ w2p,
                                             const float* __restrict__ b2,
                                             const short* __restrict__ w3p,
                                             const float* __restrict__ b3,
                                             short* __restrict__ outT, short* sm, int bid) {
    constexpr int K1 = 160, P1 = 168, NPC1 = 20, P3 = 104;
    short* Xs = sm;            // 64*168
    short* Hs = sm + 64 * P1;  // 64*104
    const int n0 = bid * 64;
    const int tid = threadIdx.x, wave = tid >> 6, lane = tid & 63;
    const int quad = lane >> 4, l16 = lane & 15;

    for (int i = tid; i < 64 * NPC1; i += 256) {
        int r = i / NPC1, p = i - r * NPC1;
        *(uint4*)(Xs + r * P1 + p * 8) = *(const uint4*)(h1 + (size_t)(n0 + r) * K1 + p * 8);
    }
    if (tid < 128) *(uint4*)(Hs + (tid >> 1) * P3 + 80 + (tid & 1) * 8) = (uint4){0u, 0u, 0u, 0u};
    __syncthreads();

    floatx4 acc[5];
#pragma unroll
    for (int mi = 0; mi < 5; mi++) acc[mi] = (floatx4){0.f, 0.f, 0.f, 0.f};
#pragma unroll
    for (int kk = 0; kk < 5; kk++) {
        short8 bb = *(const short8*)(Xs + (wave * 16 + l16) * P1 + kk * 32 + quad * 8);
#pragma unroll
        for (int mi = 0; mi < 5; mi++) {
            short8 a = *(const short8*)(w2p + ((size_t)(mi * 5 + kk)) * 512 + lane * 8);
            acc[mi] = __builtin_amdgcn_mfma_f32_16x16x32_bf16(a, bb, acc[mi], 0, 0, 0);
        }
    }
#pragma unroll
    for (int mi = 0; mi < 5; mi++) {
        int cb = mi * 16 + quad * 4;
        float4 bv = *(const float4*)(b2 + cb);
        ushort4 o;
        o.x = (unsigned short)f2bf(fmaxf(acc[mi][0] + bv.x, 0.f));
        o.y = (unsigned short)f2bf(fmaxf(acc[mi][1] + bv.y, 0.f));
        o.z = (unsigned short)f2bf(fmaxf(acc[mi][2] + bv.z, 0.f));
        o.w = (unsigned short)f2bf(fmaxf(acc[mi][3] + bv.w, 0.f));
        *(ushort4*)(Hs + (wave * 16 + l16) * P3 + cb) = o;
    }
    __syncthreads();

    floatx4 acc3[5];
#pragma unroll
    for (int mi = 0; mi < 5; mi++) acc3[mi] = (floatx4){0.f, 0.f, 0.f, 0.f};
#pragma unroll
    for (int kk = 0; kk < 3; kk++) {
        short8 bb = *(const short8*)(Hs + (wave * 16 + l16) * P3 + kk * 32 + quad * 8);
#pragma unroll
        for (int mi = 0; mi < 5; mi++) {
            short8 a = *(const short8*)(w3p + ((size_t)(mi * 3 + kk)) * 512 + lane * 8);
            acc3[mi] = __builtin_amdgcn_mfma_f32_16x16x32_bf16(a, bb, acc3[mi], 0, 0, 0);
        }
    }
    int n = n0 + wave * 16 + l16;
#pragma unroll
    for (int mi = 0; mi < 5; mi++) {
        int cb = mi * 16 + quad * 4;
        float4 bv = *(const float4*)(b3 + cb);
        ushort4 o;
        o.x = (unsigned short)f2bf(acc3[mi][0] + bv.x);
        o.y = (unsigned short)f2bf(acc3[mi][1] + bv.y);
        o.z = (unsigned short)f2bf(acc3[mi][2] + bv.z);
        o.w = (unsigned short)f2bf(acc3[mi][3] + bv.w);
        *(ushort4*)(outT + (size_t)n * ENC_STR + cb) = o;
    }
    if (quad < 2) *(uint4*)(outT + (size_t)n * ENC_STR + 80 + quad * 8) = (uint4){0u, 0u, 0u, 0u};
}

// G: key 1x1 GEMM (50 blocks) + fused query conv2+conv3 (250 blocks)
__global__ __launch_bounds__(256, 2) void gemm_kernel(
    const short* __restrict__ kh1T, const short* __restrict__ wk2p,
    const float* __restrict__ bk2, short* __restrict__ k_encT, float* __restrict__ k2ws,
    const short* __restrict__ qh1T, const short* __restrict__ wq2p,
    const float* __restrict__ bq2, const short* __restrict__ wq3p,
    const float* __restrict__ bq3, short* __restrict__ q_encT) {
    __shared__ short sm[17408];
    int bid = blockIdx.x;
    if (bid < 50) kgemm_body(kh1T, wk2p, bk2, k_encT, k2ws, sm, bid);
    else qconv23_body(qh1T, wq2p, bq2, wq3p, bq3, q_encT, sm, bid - 50);
}

// ---------------------------------------------------------------------------
// attention: LDS-free, barrier-free.  Block = 64 t1 x b, 4 waves (16 rows each).
// QK^T operands read directly from global (stride-96 padded rows, L1/L2-hit).
// q^2 cancels; k2 precomputed (k2ws); prior/mask/k2 prefetched to registers.
// Second softmax runs on u = s + log(prior) (shift-invariant), independent of
// the first chain; logp = u - m - logZ.
// ---------------------------------------------------------------------------
__device__ __forceinline__ float rmax16(float v) {
#pragma unroll
    for (int o = 1; o < 16; o <<= 1) v = fmaxf(v, __shfl_xor(v, o, 64));
    return v;
}
__device__ __forceinline__ float rsum16(float v) {
#pragma unroll
    for (int o = 1; o < 16; o <<= 1) v += __shfl_xor(v, o, 64);
    return v;
}

__global__ __launch_bounds__(256) void attn_kernel(const short* __restrict__ q_encT,
                                                   const short* __restrict__ k_encT,
                                                   const float* __restrict__ k2ws,
                                                   const float* __restrict__ prior,
                                                   const int* __restrict__ mask,
                                                   float* __restrict__ out_attn,
                                                   float* __restrict__ out_logp) {
    const int t10 = blockIdx.x * 64, b = blockIdx.y;
    const int tid = threadIdx.x, wave = tid >> 6, lane = tid & 63;
    const int quad = lane >> 4, l16 = lane & 15;

    // early register prefetches (overlap with MFMA section)
    float k2v[13]; int mskv[13];
#pragma unroll
    for (int n = 0; n < 13; n++) {
        int t2 = n * 16 + l16, t2c = t2 < T2 ? t2 : T2 - 1;
        k2v[n] = k2ws[b * T2 + t2c];
        mskv[n] = (t2 < T2) ? mask[b * T2 + t2] : 0;
    }
    const int t1base = t10 + wave * 16 + quad * 4;
    float pr[4][13];
#pragma unroll
    for (int r = 0; r < 4; r++) {
        int t1 = t1base + r, t1c = t1 < T1 ? t1 : T1 - 1;
#pragma unroll
        for (int n = 0; n < 13; n++) {
            int t2 = n * 16 + l16, t2c = t2 < T2 ? t2 : T2 - 1;
            pr[r][n] = prior[((size_t)b * T1 + t1c) * T2 + t2c];
        }
    }

    // QK^T from global fragments
    floatx4 acc[13];
#pragma unroll
    for (int n = 0; n < 13; n++) acc[n] = (floatx4){0.f, 0.f, 0.f, 0.f};
    const short* qb = q_encT + ((size_t)(b * T1 + t10 + wave * 16 + l16)) * ENC_STR + quad * 8;
    const short* kb = k_encT + ((size_t)(b * T2 + l16)) * ENC_STR + quad * 8;
#pragma unroll
    for (int kk = 0; kk < 3; kk++) {
        short8 a = *(const short8*)(qb + kk * 32);
#pragma unroll
        for (int n = 0; n < 13; n++) {
            short8 bb = *(const short8*)(kb + (size_t)n * 16 * ENC_STR + kk * 32);
            acc[n] = __builtin_amdgcn_mfma_f32_16x16x32_bf16(a, bb, acc[n], 0, 0, 0);
        }
    }

#pragma unroll
    for (int r = 0; r < 4; r++) {
        int t1 = t1base + r;
        bool t1ok = t1 < T1;
        float s[13], u[13];
        float mx = -INFINITY, mxu = -INFINITY;
#pragma unroll
        for (int n = 0; n < 13; n++) {
            int t2 = n * 16 + l16;
            float sv = (t2 < T2) ? TEMP_F * (2.f * acc[n][r] - k2v[n]) : -INFINITY;
            s[n] = sv;
            float uv = (t2 < T2) ? sv + __logf(pr[r][n] + 1e-8f) : -INFINITY;
            u[n] = uv;
            mx = fmaxf(mx, sv);
            mxu = fmaxf(mxu, (mskv[n] != 0) ? uv : -INFINITY);
        }
        float m = rmax16(mx);
        float m2 = rmax16(mxu);
        float se = 0.f, se2 = 0.f;
        float e2v[13];
#pragma unroll
        for (int n = 0; n < 13; n++) {
            se += (s[n] == -INFINITY) ? 0.f : __expf(s[n] - m);
            float e2 = (mskv[n] != 0) ? __expf(u[n] - m2) : 0.f;
            e2v[n] = e2;
            se2 += e2;
        }
        float logZ = __logf(rsum16(se));
        float invZ2 = 1.f / rsum16(se2);
        if (t1ok) {
#pragma unroll
            for (int n = 0; n < 13; n++) {
                int t2 = n * 16 + l16;
                if (t2 < T2) {
                    size_t o = ((size_t)b * T1 + t1) * T2 + t2;
                    out_attn[o] = e2v[n] * invZ2;
                    out_logp[o] = u[n] - m - logZ;
                }
            }
        }
    }
}

// ---------------------------------------------------------------------------
extern "C" void kernel_launch(void* const* d_in, const int* in_sizes, int n_in,
                              void* d_out, int out_size, void* d_ws, size_t ws_size,
                              hipStream_t stream) {
    const float* queries = (const float*)d_in[0];
    const float* keys    = (const float*)d_in[1];
    const int*   mask    = (const int*)d_in[2];
    const float* prior   = (const float*)d_in[3];
    const float* g       = (const float*)d_in[4];
    const float* wk1 = (const float*)d_in[5];
    const float* bk1 = (const float*)d_in[6];
    const float* wk2 = (const float*)d_in[7];
    const float* bk2 = (const float*)d_in[8];
    const float* wq1 = (const float*)d_in[9];
    const float* bq1 = (const float*)d_in[10];
    const float* wq2 = (const float*)d_in[11];
    const float* bq2 = (const float*)d_in[12];
    const float* wq3 = (const float*)d_in[13];
    const float* bq3 = (const float*)d_in[14];
    const float* w_kspk = (const float*)d_in[15];
    const float* b_kspk = (const float*)d_in[16];
    const float* w_qspk = (const float*)d_in[17];
    const float* b_qspk = (const float*)d_in[18];

    // ---- workspace layout (shorts) ----
    short* wsS   = (short*)d_ws;
    short* xkT   = wsS;                              // 16x200x512        -> 1,638,400
    short* xqT   = wsS + 1638400;                    // 16x1000x80        -> 2,918,400
    short* wk1p  = wsS + 2918400;                    // 3072 frags        -> 4,491,264
    short* wq1p  = wsS + 4491264;                    // 108 frags         -> 4,546,560
    short* wk2p  = wsS + 4546560;                    // 160 frags         -> 4,628,480
    short* wq2p  = wsS + 4628480;                    // 25 frags          -> 4,641,280
    short* wq3p  = wsS + 4641280;                    // 15 frags          -> 4,648,960
    short* k_encT = wsS + 4648960;                   // 3216 x 96         -> 4,957,696
    short* q_encT = wsS + 4957696;                   // 16032 x 96        -> 6,496,768
    float* k2ws  = (float*)d_ws + 3248384;           // 3200 fp32 (13 MB total)
    // hidden layers in d_out (consumed before attn overwrites):
    short* doS  = (short*)d_out;
    short* kh1T = doS;                               // 3200x1024 (6.55 MB)
    short* qh1T = doS + 3276800;                     // 16000x160 (5.12 MB)

    // P: all prep in one dispatch (2638 blocks)
    prep_kernel<<<dim3(2638), dim3(256), 0, stream>>>(
        keys, queries, g, wk1, wq1, wk2, wq2, wq3,
        w_kspk, b_kspk, w_qspk, b_qspk,
        wk1p, wq1p, wk2p, wq2p, wq3p, xkT, xqT);
    // C: both k=3 convs in one dispatch (896 blocks)
    conv_kernel<<<dim3(896), dim3(256), 0, stream>>>(xkT, wk1p, bk1, kh1T,
                                                     xqT, wq1p, bq1, qh1T);
    // G: key 1x1 GEMM (+k2) + fused query conv2/conv3 (300 blocks)
    gemm_kernel<<<dim3(300), dim3(256), 0, stream>>>(kh1T, wk2p, bk2, k_encT, k2ws,
                                                     qh1T, wq2p, bq2, wq3p, bq3, q_encT);
    // A: attention (LDS-free)
    float* out_attn = (float*)d_out;
    float* out_logp = out_attn + (size_t)NB * T1 * T2;
    attn_kernel<<<dim3(16, NB), dim3(256), 0, stream>>>(q_encT, k_encT, k2ws, prior, mask,
                                                        out_attn, out_logp);
}